// Round 3
// baseline (991.804 us; speedup 1.0000x reference)
//
#include <hip/hip_runtime.h>
#include <stdint.h>

typedef unsigned short u16;

static const int N_NODES = 131072;   // B*T*NN = 128*128*8
static const int N_EDGES = 1048576;

__device__ __forceinline__ float u2f(u16 u){
  union{uint32_t i; float f;} w; w.i = ((uint32_t)u)<<16; return w.f;
}
__device__ __forceinline__ u16 f2u(float f){
  union{float f; uint32_t u;} v; v.f=f;
  uint32_t u=v.u;
  u += 0x7fff + ((u>>16)&1);   // round-to-nearest-even
  return (u16)(u>>16);
}
// internal-buffer typed access
__device__ __forceinline__ float ldv(const float* p, int i){ return p[i]; }
__device__ __forceinline__ float ldv(const u16* p, int i){ return u2f(p[i]); }
__device__ __forceinline__ void stv(float* p, int i, float v){ p[i]=v; }
__device__ __forceinline__ void stv(u16* p, int i, float v){ p[i]=f2u(v); }
// external-input access, runtime dtype
__device__ __forceinline__ float ldmix(const void* p, int i, int isbf){
  return isbf ? u2f(((const u16*)p)[i]) : ((const float*)p)[i];
}

// ---------------- dtype detection ----------------
// bf16-packed N(0,1) data: bits 14..7 (low-half exponent) sit in [0x6F,0x85] ~always.
// fp32 data: those are mantissa bits, ~uniform (hit rate ~9%). Count over 256 words.
__global__ void k_detect(const uint32_t* __restrict__ x, int* __restrict__ flag){
  if (threadIdx.x==0 && blockIdx.x==0){
    int cnt=0;
    for (int i=0;i<256;i++){
      uint32_t e=(x[i]>>7)&0xFFu;
      if (e>=0x6Fu && e<=0x85u) cnt++;
    }
    *flag = (cnt>=128) ? 1 : 0;
  }
}

// ---------------- graph prep ----------------
__global__ __launch_bounds__(256) void k_count(const int* __restrict__ dst, int* __restrict__ deg){
  int e = blockIdx.x*256 + threadIdx.x;
  atomicAdd(&deg[dst[e] & (N_NODES-1)], 1);
}
__global__ __launch_bounds__(256) void k_dinv(const int* __restrict__ deg, float* __restrict__ dinv){
  int n = blockIdx.x*256 + threadIdx.x;
  dinv[n] = rsqrtf((float)deg[n] + 1.0f);   // +1 self loop
}
__global__ __launch_bounds__(256) void k_scan1(const int* __restrict__ deg, int* __restrict__ offs,
                                               int* __restrict__ bsum){
  __shared__ int sh[256];
  int t = threadIdx.x, i = blockIdx.x*256 + t;
  int v = deg[i]; sh[t] = v; __syncthreads();
  for (int d=1; d<256; d<<=1){
    int o = (t>=d) ? sh[t-d] : 0; __syncthreads();
    sh[t] += o; __syncthreads();
  }
  offs[i] = sh[t] - v;
  if (t==255) bsum[blockIdx.x] = sh[t];
}
__global__ __launch_bounds__(512) void k_scan2(int* __restrict__ bsum){
  __shared__ int sh[512];
  int t = threadIdx.x;
  int v = bsum[t]; sh[t] = v; __syncthreads();
  for (int d=1; d<512; d<<=1){
    int o = (t>=d) ? sh[t-d] : 0; __syncthreads();
    sh[t] += o; __syncthreads();
  }
  bsum[t] = sh[t] - v;
}
__global__ __launch_bounds__(256) void k_scan3(int* __restrict__ offs, const int* __restrict__ bsum){
  int i = blockIdx.x*256 + threadIdx.x;
  offs[i] += bsum[blockIdx.x];
}
__global__ __launch_bounds__(256) void k_fill(const int* __restrict__ src, const int* __restrict__ dst,
                                              const int* __restrict__ offs, int* __restrict__ cur,
                                              int* __restrict__ adj){
  int e = blockIdx.x*256 + threadIdx.x;
  int d = dst[e] & (N_NODES-1);
  int p = atomicAdd(&cur[d], 1);
  int idx = offs[d] + p;
  if (idx >= 0 && idx < N_EDGES) adj[idx] = src[e] & (N_NODES-1);
}

// ---- GCN aggregation, layer 1 (external input, F=32) ----
template<typename TO>
__global__ __launch_bounds__(256) void k_agg_in(const void* __restrict__ X, const int* __restrict__ flag,
                                                const int* __restrict__ adj, const int* __restrict__ offs,
                                                const int* __restrict__ deg, const float* __restrict__ dinv,
                                                TO* __restrict__ out){
  int isbf = *flag;
  int c = threadIdx.x & 31;
  int slot = threadIdx.x >> 5;
  int n = blockIdx.x*8 + slot;
  float dn = dinv[n];
  int o = offs[n] & (N_EDGES-1);
  int cnt = min(deg[n], 8192);
  float acc;
  if (isbf){
    const u16* Xb = (const u16*)X;
    acc = dn * u2f(Xb[n*32+c]);
    for (int e=0;e<cnt;e++){ int s = adj[o+e] & (N_NODES-1); acc += dinv[s]*u2f(Xb[s*32+c]); }
  } else {
    const float* Xf = (const float*)X;
    acc = dn * Xf[n*32+c];
    for (int e=0;e<cnt;e++){ int s = adj[o+e] & (N_NODES-1); acc += dinv[s]*Xf[s*32+c]; }
  }
  stv(out, n*32+c, dn*acc);
}

// ---- GCN aggregation, layer 2 (internal input, F=64) ----
template<typename T>
__global__ __launch_bounds__(256) void k_agg_T(const T* __restrict__ X,
                                               const int* __restrict__ adj, const int* __restrict__ offs,
                                               const int* __restrict__ deg, const float* __restrict__ dinv,
                                               T* __restrict__ out){
  int c = threadIdx.x & 63;
  int slot = threadIdx.x >> 6;
  int n = blockIdx.x*4 + slot;
  float dn = dinv[n];
  float acc = dn * ldv(X, n*64+c);
  int o = offs[n] & (N_EDGES-1);
  int cnt = min(deg[n], 8192);
  for (int e=0;e<cnt;e++){
    int s = adj[o+e] & (N_NODES-1);
    acc += dinv[s] * ldv(X, s*64+c);
  }
  stv(out, n*64+c, dn*acc);
}

// ---- linear: out[n,co] = bias[co] + sum_k A[n,k]*W[k,co] ----
template<int K, typename T>
__global__ __launch_bounds__(256) void k_linear(const T* __restrict__ A, const void* __restrict__ W,
                                                const void* __restrict__ bias, const int* __restrict__ flag,
                                                T* __restrict__ out){
  __shared__ float Ws[K*64];
  int isbf = *flag;
  for (int i=threadIdx.x; i<K*64; i+=256) Ws[i] = ldmix(W, i, isbf);
  __syncthreads();
  int co = threadIdx.x & 63;
  int slot = threadIdx.x >> 6;
  float bv = ldmix(bias, co, isbf);
  for (int row = blockIdx.x*4 + slot; row < N_NODES; row += gridDim.x*4){
    float acc = bv;
    #pragma unroll
    for (int k=0; k<K; k++) acc += ldv(A, row*K + k)*Ws[k*64+co];
    stv(out, row*64 + co, acc);
  }
}

// ---- temporal conv (1,3), pad 1 ; t-tile = 32 (LDS: 8704 + 49152 = 57856 B) ----
template<typename T>
__global__ __launch_bounds__(256) void k_tconv(const T* __restrict__ X, const void* __restrict__ W,
                                               const void* __restrict__ bias, const int* __restrict__ flag,
                                               T* __restrict__ out){
  __shared__ float a_s[34*64];          // rows t0-1 .. t0+32
  __shared__ float w_s[3*64*64];        // [k][ci][co]
  int isbf = *flag;
  int bid = blockIdx.x;                 // b*32 + v*4 + tq
  int b = bid>>5, rem = bid&31, v = rem>>2, tq = rem&3;
  int t0 = tq<<5;
  for (int i=threadIdx.x; i<3*64*64; i+=256){
    int k = i>>12, r = i&4095, ci = r>>6, co = r&63;
    w_s[i] = ldmix(W, co*192 + ci*3 + k, isbf);
  }
  for (int i=threadIdx.x; i<34*64; i+=256){
    int rr = i>>6, ci = i&63;
    int t = t0 + rr - 1;
    float val = 0.f;
    if (t >= 0 && t < 128) val = ldv(X, (((b*128+t)*8+v)<<6) + ci);
    a_s[i] = val;
  }
  __syncthreads();
  int wg = threadIdx.x>>6, co = threadIdx.x&63;
  float bv = ldmix(bias, co, isbf);
  float acc[8];
  #pragma unroll
  for (int tt=0; tt<8; tt++) acc[tt] = bv;
  for (int ci=0; ci<64; ci++){
    float ar[10];
    #pragma unroll
    for (int j=0; j<10; j++) ar[j] = a_s[((wg*8+j)<<6) + ci];
    #pragma unroll
    for (int k=0; k<3; k++){
      float wgt = w_s[(k<<12) + (ci<<6) + co];
      #pragma unroll
      for (int tt=0; tt<8; tt++) acc[tt] += wgt*ar[tt+k];
    }
  }
  #pragma unroll
  for (int tt=0; tt<8; tt++){
    int t = t0 + wg*8 + tt;
    stv(out, (((b*128+t)*8+v)<<6) + co, acc[tt]);
  }
}

// ---- BN stats: per-channel sum / sumsq ----
template<typename T>
__global__ __launch_bounds__(256) void k_stats(const T* __restrict__ X, float* __restrict__ stats){
  int co = threadIdx.x & 63, g = threadIdx.x >> 6;
  float s = 0.f, s2 = 0.f;
  for (int row = blockIdx.x*4 + g; row < N_NODES; row += gridDim.x*4){
    float v = ldv(X, (row<<6) + co);
    s += v; s2 += v*v;
  }
  __shared__ float sh[512];
  sh[threadIdx.x] = s; sh[256+threadIdx.x] = s2;
  __syncthreads();
  if (g == 0){
    s  = sh[co] + sh[64+co] + sh[128+co] + sh[192+co];
    s2 = sh[256+co] + sh[320+co] + sh[384+co] + sh[448+co];
    atomicAdd(&stats[co], s);
    atomicAdd(&stats[64+co], s2);
  }
}

// ---- BN-apply + ReLU + 1x1 conv + tanh + scrambled view(-1,64) write ----
template<typename T>
__global__ __launch_bounds__(256) void k_bnfuse(const T* __restrict__ X, const float* __restrict__ stats,
                                                const void* __restrict__ gam, const void* __restrict__ bet,
                                                const void* __restrict__ ow, const void* __restrict__ ob,
                                                const int* __restrict__ flag, T* __restrict__ out){
  __shared__ float y_s[64*65];
  __shared__ float ow_s[64*64];    // [co][ci]
  __shared__ float kk[64], bsh[64];
  int isbf = *flag;
  int bid = blockIdx.x;
  int b = bid>>4, rem = bid&15, v = rem>>1, thi = rem&1;
  int t0 = thi<<6;
  const float invM = 1.0f/131072.0f;
  if (threadIdx.x < 64){
    int ci = threadIdx.x;
    float mu = stats[ci]*invM;
    float var = stats[64+ci]*invM - mu*mu;
    float rs = rsqrtf(fmaxf(var, 0.f) + 1e-5f);
    float kv = rs*ldmix(gam, ci, isbf);
    kk[ci] = kv;
    bsh[ci] = ldmix(bet, ci, isbf) - mu*kv;
  }
  for (int i=threadIdx.x; i<4096; i+=256) ow_s[i] = ldmix(ow, i, isbf);
  __syncthreads();
  for (int i=threadIdx.x; i<4096; i+=256){
    int tl = i>>6, ci = i&63;
    int t = t0 + tl;
    float val = ldv(X, (((b*128+t)*8+v)<<6) + ci);
    val = val*kk[ci] + bsh[ci];
    y_s[tl*65 + ci] = fmaxf(val, 0.f);
  }
  __syncthreads();
  int l = threadIdx.x & 63, wg = threadIdx.x >> 6;
  float acc[16];
  #pragma unroll
  for (int c8=0; c8<16; c8++) acc[c8] = ldmix(ob, wg*16 + c8, isbf);
  for (int ci=0; ci<64; ci++){
    float yv = y_s[l*65 + ci];
    #pragma unroll
    for (int c8=0; c8<16; c8++) acc[c8] += ow_s[((wg*16+c8)<<6) + ci]*yv;
  }
  #pragma unroll
  for (int c8=0; c8<16; c8++){
    int co = wg*16 + c8;
    float z = tanhf(acc[c8]);
    // x_next[r, l]  with  r = b*1024 + co*16 + v*2 + thi   (faithful view(-1,64))
    int r = (b<<10) + (co<<4) + (v<<1) + thi;
    stv(out, (r<<6) + l, z);
  }
}

// ---- final: out[b,v] = mean_{t,f}( x3 @ reg_w + reg_b ) ----
template<typename T>
__global__ __launch_bounds__(256) void k_final(const T* __restrict__ X, const void* __restrict__ rw,
                                               const void* __restrict__ rb, const int* __restrict__ flag,
                                               void* __restrict__ out){
  __shared__ float rw_s[64];
  __shared__ float rbs_s;
  __shared__ float wred[4];
  int isbf = *flag;
  int bid = blockIdx.x;
  int b = bid>>3, v = bid&7;
  if (threadIdx.x < 64){
    float s = 0.f;
    #pragma unroll
    for (int f=0; f<8; f++) s += ldmix(rw, threadIdx.x*8 + f, isbf);
    rw_s[threadIdx.x] = s;
  }
  if (threadIdx.x == 0){
    float s = 0.f;
    for (int f=0; f<8; f++) s += ldmix(rb, f, isbf);
    rbs_s = s;
  }
  __syncthreads();
  float acc = 0.f;
  for (int i=threadIdx.x; i<128*64; i+=256){
    int t = i>>6, j = i&63;
    acc += ldv(X, (((b*128+t)*8+v)<<6) + j) * rw_s[j];
  }
  for (int off=32; off; off>>=1) acc += __shfl_down(acc, off);
  if ((threadIdx.x & 63) == 0) wred[threadIdx.x>>6] = acc;
  __syncthreads();
  if (threadIdx.x == 0){
    float r = wred[0]+wred[1]+wred[2]+wred[3];
    float val = r*(1.0f/1024.0f) + rbs_s*0.125f;
    if (isbf) ((u16*)out)[bid] = f2u(val);
    else      ((float*)out)[bid] = val;
  }
}

// ---------------- host pipeline (T = ping-pong buffer element type) ----------------
template<typename T>
static void run_pipe(void* const* d_in, void* out, char* p, hipStream_t stream){
  auto alloc = [&](size_t bytes){ void* r = (void*)p; p += (bytes + 255) & ~(size_t)255; return r; };
  T*     A    = (T*)    alloc(sizeof(T)*(size_t)N_NODES*64);
  T*     B    = (T*)    alloc(sizeof(T)*(size_t)N_NODES*64);
  int*   deg  = (int*)  alloc(sizeof(int)*N_NODES);
  float* dinv = (float*)alloc(sizeof(float)*N_NODES);
  int*   offs = (int*)  alloc(sizeof(int)*N_NODES);
  int*   cur  = (int*)  alloc(sizeof(int)*N_NODES);
  int*   adj  = (int*)  alloc(sizeof(int)*N_EDGES);
  int*   bsum = (int*)  alloc(sizeof(int)*512);
  float* stats= (float*)alloc(sizeof(float)*128);
  int*   flag = (int*)  alloc(sizeof(int)*64);

  const void* x   = d_in[0];
  const int* edge = (const int*)d_in[1];
  const void* g1w = d_in[2];  const void* g1b = d_in[3];
  const void* t1w = d_in[4];  const void* t1b = d_in[5];
  const void* bn1g= d_in[6];  const void* bn1b= d_in[7];
  const void* o1w = d_in[8];  const void* o1b = d_in[9];
  const void* g2w = d_in[10]; const void* g2b = d_in[11];
  const void* t2w = d_in[12]; const void* t2b = d_in[13];
  const void* bn2g= d_in[14]; const void* bn2b= d_in[15];
  const void* o2w = d_in[16]; const void* o2b = d_in[17];
  const void* rw  = d_in[18]; const void* rb  = d_in[19];
  const int* src = edge;
  const int* dst = edge + N_EDGES;

  k_detect<<<1, 64, 0, stream>>>((const uint32_t*)x, flag);

  // graph prep (shared by both layers)
  hipMemsetAsync(deg, 0, sizeof(int)*N_NODES, stream);
  k_count<<<N_EDGES/256, 256, 0, stream>>>(dst, deg);
  k_dinv <<<N_NODES/256, 256, 0, stream>>>(deg, dinv);
  k_scan1<<<512, 256, 0, stream>>>(deg, offs, bsum);
  k_scan2<<<1, 512, 0, stream>>>(bsum);
  k_scan3<<<512, 256, 0, stream>>>(offs, bsum);
  hipMemsetAsync(cur, 0, sizeof(int)*N_NODES, stream);
  k_fill <<<N_EDGES/256, 256, 0, stream>>>(src, dst, offs, cur, adj);

  // ---- layer 1 ----  (aggregate first: A(XW) == (AX)W, gathers 32-wide rows)
  k_agg_in<T>   <<<N_NODES/8, 256, 0, stream>>>(x, flag, adj, offs, deg, dinv, A);
  k_linear<32,T><<<2048, 256, 0, stream>>>(A, g1w, g1b, flag, B);
  k_tconv<T>    <<<4096, 256, 0, stream>>>(B, t1w, t1b, flag, A);
  hipMemsetAsync(stats, 0, sizeof(float)*128, stream);
  k_stats<T>    <<<256, 256, 0, stream>>>(A, stats);
  k_bnfuse<T>   <<<2048, 256, 0, stream>>>(A, stats, bn1g, bn1b, o1w, o1b, flag, B);

  // ---- layer 2 ----
  k_agg_T<T>    <<<N_NODES/4, 256, 0, stream>>>(B, adj, offs, deg, dinv, A);
  k_linear<64,T><<<2048, 256, 0, stream>>>(A, g2w, g2b, flag, B);
  k_tconv<T>    <<<4096, 256, 0, stream>>>(B, t2w, t2b, flag, A);
  hipMemsetAsync(stats, 0, sizeof(float)*128, stream);
  k_stats<T>    <<<256, 256, 0, stream>>>(A, stats);
  k_bnfuse<T>   <<<2048, 256, 0, stream>>>(A, stats, bn2g, bn2b, o2w, o2b, flag, B);

  // ---- regression + mean ----
  k_final<T><<<1024, 256, 0, stream>>>(B, rw, rb, flag, out);
}

extern "C" void kernel_launch(void* const* d_in, const int* in_sizes, int n_in,
                              void* d_out, int out_size, void* d_ws, size_t ws_size,
                              hipStream_t stream){
  (void)in_sizes; (void)n_in; (void)out_size;
  const size_t csr_bytes = 4*sizeof(int)*(size_t)N_NODES + sizeof(int)*(size_t)N_EDGES + 32768;
  const size_t need_f32  = 2*sizeof(float)*(size_t)N_NODES*64 + csr_bytes;   // ~73.4 MB
  if (ws_size >= need_f32)
    run_pipe<float>(d_in, d_out, (char*)d_ws, stream);
  else
    run_pipe<u16>(d_in, d_out, (char*)d_ws, stream);     // ~40 MB fallback
}

// Round 4
// 668.941 us; speedup vs baseline: 1.4826x; 1.4826x over previous
//
#include <hip/hip_runtime.h>
#include <stdint.h>

typedef unsigned short u16;

static const int N_NODES = 131072;   // B*T*NN = 128*128*8
static const int N_EDGES = 1048576;

__device__ __forceinline__ float u2f(u16 u){
  union{uint32_t i; float f;} w; w.i = ((uint32_t)u)<<16; return w.f;
}
__device__ __forceinline__ u16 f2u(float f){
  union{float f; uint32_t u;} v; v.f=f;
  uint32_t u=v.u;
  u += 0x7fff + ((u>>16)&1);   // round-to-nearest-even
  return (u16)(u>>16);
}
// internal-buffer typed access
__device__ __forceinline__ float ldv(const float* p, int i){ return p[i]; }
__device__ __forceinline__ float ldv(const u16* p, int i){ return u2f(p[i]); }
__device__ __forceinline__ void stv(float* p, int i, float v){ p[i]=v; }
__device__ __forceinline__ void stv(u16* p, int i, float v){ p[i]=f2u(v); }
// external-input access, runtime dtype
__device__ __forceinline__ float ldmix(const void* p, int i, int isbf){
  return isbf ? u2f(((const u16*)p)[i]) : ((const float*)p)[i];
}

// ---------------- dtype detection ----------------
__global__ void k_detect(const uint32_t* __restrict__ x, int* __restrict__ flag){
  if (threadIdx.x==0 && blockIdx.x==0){
    int cnt=0;
    for (int i=0;i<256;i++){
      uint32_t e=(x[i]>>7)&0xFFu;
      if (e>=0x6Fu && e<=0x85u) cnt++;
    }
    *flag = (cnt>=128) ? 1 : 0;
  }
}

// ---------------- graph prep ----------------
__global__ __launch_bounds__(256) void k_count(const int* __restrict__ dst, int* __restrict__ deg){
  int e = blockIdx.x*256 + threadIdx.x;
  atomicAdd(&deg[dst[e] & (N_NODES-1)], 1);
}
__global__ __launch_bounds__(256) void k_dinv(const int* __restrict__ deg, float* __restrict__ dinv){
  int n = blockIdx.x*256 + threadIdx.x;
  dinv[n] = rsqrtf((float)deg[n] + 1.0f);   // +1 self loop
}
__global__ __launch_bounds__(256) void k_scan1(const int* __restrict__ deg, int* __restrict__ offs,
                                               int* __restrict__ bsum){
  __shared__ int sh[256];
  int t = threadIdx.x, i = blockIdx.x*256 + t;
  int v = deg[i]; sh[t] = v; __syncthreads();
  for (int d=1; d<256; d<<=1){
    int o = (t>=d) ? sh[t-d] : 0; __syncthreads();
    sh[t] += o; __syncthreads();
  }
  offs[i] = sh[t] - v;
  if (t==255) bsum[blockIdx.x] = sh[t];
}
__global__ __launch_bounds__(512) void k_scan2(int* __restrict__ bsum){
  __shared__ int sh[512];
  int t = threadIdx.x;
  int v = bsum[t]; sh[t] = v; __syncthreads();
  for (int d=1; d<512; d<<=1){
    int o = (t>=d) ? sh[t-d] : 0; __syncthreads();
    sh[t] += o; __syncthreads();
  }
  bsum[t] = sh[t] - v;
}
__global__ __launch_bounds__(256) void k_scan3(int* __restrict__ offs, const int* __restrict__ bsum){
  int i = blockIdx.x*256 + threadIdx.x;
  offs[i] += bsum[blockIdx.x];
}
__global__ __launch_bounds__(256) void k_fill(const int* __restrict__ src, const int* __restrict__ dst,
                                              const int* __restrict__ offs, int* __restrict__ cur,
                                              int* __restrict__ adj){
  int e = blockIdx.x*256 + threadIdx.x;
  int d = dst[e] & (N_NODES-1);
  int p = atomicAdd(&cur[d], 1);
  int idx = offs[d] + p;
  if (idx >= 0 && idx < N_EDGES) adj[idx] = src[e] & (N_NODES-1);
}

// ---- GCN aggregation, layer 1 (external input, F=32) ----
template<typename TO>
__global__ __launch_bounds__(256) void k_agg_in(const void* __restrict__ X, const int* __restrict__ flag,
                                                const int* __restrict__ adj, const int* __restrict__ offs,
                                                const int* __restrict__ deg, const float* __restrict__ dinv,
                                                TO* __restrict__ out){
  int isbf = *flag;
  int c = threadIdx.x & 31;
  int slot = threadIdx.x >> 5;
  int n = blockIdx.x*8 + slot;
  float dn = dinv[n];
  int o = offs[n] & (N_EDGES-1);
  int cnt = min(deg[n], 8192);
  float acc;
  if (isbf){
    const u16* Xb = (const u16*)X;
    acc = dn * u2f(Xb[n*32+c]);
    for (int e=0;e<cnt;e++){ int s = adj[o+e] & (N_NODES-1); acc += dinv[s]*u2f(Xb[s*32+c]); }
  } else {
    const float* Xf = (const float*)X;
    acc = dn * Xf[n*32+c];
    for (int e=0;e<cnt;e++){ int s = adj[o+e] & (N_NODES-1); acc += dinv[s]*Xf[s*32+c]; }
  }
  stv(out, n*32+c, dn*acc);
}

// ---- GCN aggregation, layer 2 (internal input, F=64) ----
template<typename T>
__global__ __launch_bounds__(256) void k_agg_T(const T* __restrict__ X,
                                               const int* __restrict__ adj, const int* __restrict__ offs,
                                               const int* __restrict__ deg, const float* __restrict__ dinv,
                                               T* __restrict__ out){
  int c = threadIdx.x & 63;
  int slot = threadIdx.x >> 6;
  int n = blockIdx.x*4 + slot;
  float dn = dinv[n];
  float acc = dn * ldv(X, n*64+c);
  int o = offs[n] & (N_EDGES-1);
  int cnt = min(deg[n], 8192);
  for (int e=0;e<cnt;e++){
    int s = adj[o+e] & (N_NODES-1);
    acc += dinv[s] * ldv(X, s*64+c);
  }
  stv(out, n*64+c, dn*acc);
}

// ---- combine GCN weight with temporal-conv weight ----
// W2[k*Kin + j][co] = sum_c gW[j*64+c] * tw[co*192 + c*3 + k]      (Kin=32: gW is [32,64])
// braw[k*64 + co]   = sum_c gb[c]      * tw[co*192 + c*3 + k]
template<int Kin>
__global__ __launch_bounds__(64) void k_wcomb(const void* __restrict__ gW, const void* __restrict__ gb,
                                              const void* __restrict__ tw, const int* __restrict__ flag,
                                              float* __restrict__ W2, float* __restrict__ braw){
  int isbf = *flag;
  int r = blockIdx.x;
  int co = threadIdx.x;
  if (r < 3*Kin){
    int k = r / Kin, j = r % Kin;
    float acc = 0.f;
    for (int c=0; c<64; c++)
      acc += ldmix(gW, j*64+c, isbf) * ldmix(tw, co*192 + c*3 + k, isbf);
    W2[r*64 + co] = acc;
  } else {
    int k = r - 3*Kin;
    float acc = 0.f;
    for (int c=0; c<64; c++)
      acc += ldmix(gb, c, isbf) * ldmix(tw, co*192 + c*3 + k, isbf);
    braw[k*64 + co] = acc;
  }
}

// ---- fused linear+temporal-conv as GEMM: out[n,co] = tb[co] + sum_k sum_j A[t+k-1][j]*W2_k[j][co] ----
// block: (b, v, co-half). tile 128t x 32co. thread = 4t x 4co. A staged transposed [j][t+1] stride 132.
template<int Kin, typename T>
__global__ __launch_bounds__(256) void k_tconv2(const T* __restrict__ A, const float* __restrict__ W2,
                                                const float* __restrict__ braw, const void* __restrict__ tb,
                                                const int* __restrict__ flag, T* __restrict__ out){
  __shared__ float At[Kin][132];        // s = t+1 in [0,129]
  __shared__ float Ws[3*Kin][32];
  int isbf = *flag;
  int bid = blockIdx.x;
  int half = bid & 1, g = bid >> 1;
  int b = g >> 3, v = g & 7;
  const int tid = threadIdx.x;

  // stage weights (co-half columns)
  for (int i = tid; i < 3*Kin*32; i += 256){
    int r = i >> 5, c = i & 31;
    Ws[r][c] = W2[r*64 + half*32 + c];
  }
  // stage A transposed
  constexpr int SH = (Kin == 64) ? 6 : 5;
  for (int i = tid; i < 130*Kin; i += 256){
    int s = i >> SH, j = i & (Kin-1);
    int t = s - 1;
    float val = 0.f;
    if (t >= 0 && t < 128) val = ldv(A, (((b*128+t)*8+v) << SH) + j);
    At[j][s] = val;
  }
  __syncthreads();

  int tgroup = tid >> 3;        // 0..31 -> t0 = 4*tgroup
  int cog    = tid & 7;         // 0..7  -> co_local = 4*cog
  int t0 = tgroup << 2;
  int co0 = half*32 + (cog << 2);

  float acc[4][4];
  #pragma unroll
  for (int cc=0; cc<4; cc++){
    float b0 = braw[co0+cc], b1 = braw[64+co0+cc], b2 = braw[128+co0+cc];
    float ball = ldmix(tb, co0+cc, isbf) + b0 + b1 + b2;
    #pragma unroll
    for (int tt=0; tt<4; tt++){
      int t = t0 + tt;
      float bv = ball;
      if (t == 0)   bv -= b0;
      if (t == 127) bv -= b2;
      acc[tt][cc] = bv;
    }
  }

  for (int j = 0; j < Kin; j++){
    float4 a4 = *(const float4*)&At[j][t0];      // s = t0..t0+3
    float2 a2 = *(const float2*)&At[j][t0+4];    // s = t0+4..t0+5
    float a6[6] = {a4.x, a4.y, a4.z, a4.w, a2.x, a2.y};
    #pragma unroll
    for (int k=0; k<3; k++){
      float4 w = *(const float4*)&Ws[k*Kin + j][cog << 2];
      float wv[4] = {w.x, w.y, w.z, w.w};
      #pragma unroll
      for (int tt=0; tt<4; tt++){
        float av = a6[tt + k];                   // s = (t0+tt) + k  ==  t + (k-1) + 1
        #pragma unroll
        for (int cc=0; cc<4; cc++) acc[tt][cc] += av * wv[cc];
      }
    }
  }

  #pragma unroll
  for (int tt=0; tt<4; tt++){
    int t = t0 + tt;
    int base = (((b*128+t)*8+v) << 6) + co0;
    #pragma unroll
    for (int cc=0; cc<4; cc++) stv(out, base + cc, acc[tt][cc]);
  }
}

// ---- BN stats: per-channel sum / sumsq ----
template<typename T>
__global__ __launch_bounds__(256) void k_stats(const T* __restrict__ X, float* __restrict__ stats){
  int co = threadIdx.x & 63, g = threadIdx.x >> 6;
  float s = 0.f, s2 = 0.f;
  for (int row = blockIdx.x*4 + g; row < N_NODES; row += gridDim.x*4){
    float v = ldv(X, (row<<6) + co);
    s += v; s2 += v*v;
  }
  __shared__ float sh[512];
  sh[threadIdx.x] = s; sh[256+threadIdx.x] = s2;
  __syncthreads();
  if (g == 0){
    s  = sh[co] + sh[64+co] + sh[128+co] + sh[192+co];
    s2 = sh[256+co] + sh[320+co] + sh[384+co] + sh[448+co];
    atomicAdd(&stats[co], s);
    atomicAdd(&stats[64+co], s2);
  }
}

// ---- BN-apply + ReLU + 1x1 conv + tanh + scrambled view(-1,64) write ----
template<typename T>
__global__ __launch_bounds__(256) void k_bnfuse(const T* __restrict__ X, const float* __restrict__ stats,
                                                const void* __restrict__ gam, const void* __restrict__ bet,
                                                const void* __restrict__ ow, const void* __restrict__ ob,
                                                const int* __restrict__ flag, T* __restrict__ out){
  __shared__ float y_s[64*65];
  __shared__ float ow_s[64*64];    // [co][ci]
  __shared__ float kk[64], bsh[64];
  int isbf = *flag;
  int bid = blockIdx.x;
  int b = bid>>4, rem = bid&15, v = rem>>1, thi = rem&1;
  int t0 = thi<<6;
  const float invM = 1.0f/131072.0f;
  if (threadIdx.x < 64){
    int ci = threadIdx.x;
    float mu = stats[ci]*invM;
    float var = stats[64+ci]*invM - mu*mu;
    float rs = rsqrtf(fmaxf(var, 0.f) + 1e-5f);
    float kv = rs*ldmix(gam, ci, isbf);
    kk[ci] = kv;
    bsh[ci] = ldmix(bet, ci, isbf) - mu*kv;
  }
  for (int i=threadIdx.x; i<4096; i+=256) ow_s[i] = ldmix(ow, i, isbf);
  __syncthreads();
  for (int i=threadIdx.x; i<4096; i+=256){
    int tl = i>>6, ci = i&63;
    int t = t0 + tl;
    float val = ldv(X, (((b*128+t)*8+v)<<6) + ci);
    val = val*kk[ci] + bsh[ci];
    y_s[tl*65 + ci] = fmaxf(val, 0.f);
  }
  __syncthreads();
  int l = threadIdx.x & 63, wg = threadIdx.x >> 6;
  float acc[16];
  #pragma unroll
  for (int c8=0; c8<16; c8++) acc[c8] = ldmix(ob, wg*16 + c8, isbf);
  for (int ci=0; ci<64; ci++){
    float yv = y_s[l*65 + ci];
    #pragma unroll
    for (int c8=0; c8<16; c8++) acc[c8] += ow_s[((wg*16+c8)<<6) + ci]*yv;
  }
  #pragma unroll
  for (int c8=0; c8<16; c8++){
    int co = wg*16 + c8;
    float z = tanhf(acc[c8]);
    int r = (b<<10) + (co<<4) + (v<<1) + thi;
    stv(out, (r<<6) + l, z);
  }
}

// ---- final: out[b,v] = mean_{t,f}( x3 @ reg_w + reg_b ) ----
template<typename T>
__global__ __launch_bounds__(256) void k_final(const T* __restrict__ X, const void* __restrict__ rw,
                                               const void* __restrict__ rb, const int* __restrict__ flag,
                                               void* __restrict__ out){
  __shared__ float rw_s[64];
  __shared__ float rbs_s;
  __shared__ float wred[4];
  int isbf = *flag;
  int bid = blockIdx.x;
  int b = bid>>3, v = bid&7;
  if (threadIdx.x < 64){
    float s = 0.f;
    #pragma unroll
    for (int f=0; f<8; f++) s += ldmix(rw, threadIdx.x*8 + f, isbf);
    rw_s[threadIdx.x] = s;
  }
  if (threadIdx.x == 0){
    float s = 0.f;
    for (int f=0; f<8; f++) s += ldmix(rb, f, isbf);
    rbs_s = s;
  }
  __syncthreads();
  float acc = 0.f;
  for (int i=threadIdx.x; i<128*64; i+=256){
    int t = i>>6, j = i&63;
    acc += ldv(X, (((b*128+t)*8+v)<<6) + j) * rw_s[j];
  }
  for (int off=32; off; off>>=1) acc += __shfl_down(acc, off);
  if ((threadIdx.x & 63) == 0) wred[threadIdx.x>>6] = acc;
  __syncthreads();
  if (threadIdx.x == 0){
    float r = wred[0]+wred[1]+wred[2]+wred[3];
    float val = r*(1.0f/1024.0f) + rbs_s*0.125f;
    if (isbf) ((u16*)out)[bid] = f2u(val);
    else      ((float*)out)[bid] = val;
  }
}

// ---------------- host pipeline ----------------
template<typename T>
static void run_pipe(void* const* d_in, void* out, char* p, hipStream_t stream){
  auto alloc = [&](size_t bytes){ void* r = (void*)p; p += (bytes + 255) & ~(size_t)255; return r; };
  T*     A    = (T*)    alloc(sizeof(T)*(size_t)N_NODES*64);
  T*     B    = (T*)    alloc(sizeof(T)*(size_t)N_NODES*64);
  int*   deg  = (int*)  alloc(sizeof(int)*N_NODES);
  float* dinv = (float*)alloc(sizeof(float)*N_NODES);
  int*   offs = (int*)  alloc(sizeof(int)*N_NODES);
  int*   cur  = (int*)  alloc(sizeof(int)*N_NODES);
  int*   adj  = (int*)  alloc(sizeof(int)*N_EDGES);
  int*   bsum = (int*)  alloc(sizeof(int)*512);
  float* stats= (float*)alloc(sizeof(float)*128);
  int*   flag = (int*)  alloc(sizeof(int)*64);
  float* W2ws = (float*)alloc(sizeof(float)*192*64);
  float* braw = (float*)alloc(sizeof(float)*192);

  const void* x   = d_in[0];
  const int* edge = (const int*)d_in[1];
  const void* g1w = d_in[2];  const void* g1b = d_in[3];
  const void* t1w = d_in[4];  const void* t1b = d_in[5];
  const void* bn1g= d_in[6];  const void* bn1b= d_in[7];
  const void* o1w = d_in[8];  const void* o1b = d_in[9];
  const void* g2w = d_in[10]; const void* g2b = d_in[11];
  const void* t2w = d_in[12]; const void* t2b = d_in[13];
  const void* bn2g= d_in[14]; const void* bn2b= d_in[15];
  const void* o2w = d_in[16]; const void* o2b = d_in[17];
  const void* rw  = d_in[18]; const void* rb  = d_in[19];
  const int* src = edge;
  const int* dst = edge + N_EDGES;

  k_detect<<<1, 64, 0, stream>>>((const uint32_t*)x, flag);

  // graph prep
  hipMemsetAsync(deg, 0, sizeof(int)*N_NODES, stream);
  k_count<<<N_EDGES/256, 256, 0, stream>>>(dst, deg);
  k_dinv <<<N_NODES/256, 256, 0, stream>>>(deg, dinv);
  k_scan1<<<512, 256, 0, stream>>>(deg, offs, bsum);
  k_scan2<<<1, 512, 0, stream>>>(bsum);
  k_scan3<<<512, 256, 0, stream>>>(offs, bsum);
  hipMemsetAsync(cur, 0, sizeof(int)*N_NODES, stream);
  k_fill <<<N_EDGES/256, 256, 0, stream>>>(src, dst, offs, cur, adj);

  // ---- layer 1 ----
  k_agg_in<T>    <<<N_NODES/8, 256, 0, stream>>>(x, flag, adj, offs, deg, dinv, A);
  k_wcomb<32>    <<<3*32+3, 64, 0, stream>>>(g1w, g1b, t1w, flag, W2ws, braw);
  k_tconv2<32,T> <<<2048, 256, 0, stream>>>(A, W2ws, braw, t1b, flag, B);
  hipMemsetAsync(stats, 0, sizeof(float)*128, stream);
  k_stats<T>     <<<512, 256, 0, stream>>>(B, stats);
  k_bnfuse<T>    <<<2048, 256, 0, stream>>>(B, stats, bn1g, bn1b, o1w, o1b, flag, A);

  // ---- layer 2 ----
  k_agg_T<T>     <<<N_NODES/4, 256, 0, stream>>>(A, adj, offs, deg, dinv, B);
  k_wcomb<64>    <<<3*64+3, 64, 0, stream>>>(g2w, g2b, t2w, flag, W2ws, braw);
  k_tconv2<64,T> <<<2048, 256, 0, stream>>>(B, W2ws, braw, t2b, flag, A);
  hipMemsetAsync(stats, 0, sizeof(float)*128, stream);
  k_stats<T>     <<<512, 256, 0, stream>>>(A, stats);
  k_bnfuse<T>    <<<2048, 256, 0, stream>>>(A, stats, bn2g, bn2b, o2w, o2b, flag, B);

  // ---- regression + mean ----
  k_final<T><<<1024, 256, 0, stream>>>(B, rw, rb, flag, out);
}

extern "C" void kernel_launch(void* const* d_in, const int* in_sizes, int n_in,
                              void* d_out, int out_size, void* d_ws, size_t ws_size,
                              hipStream_t stream){
  (void)in_sizes; (void)n_in; (void)out_size;
  const size_t csr_bytes = 4*sizeof(int)*(size_t)N_NODES + sizeof(int)*(size_t)N_EDGES + 131072;
  const size_t need_f32  = 2*sizeof(float)*(size_t)N_NODES*64 + csr_bytes;   // ~73.5 MB
  if (ws_size >= need_f32)
    run_pipe<float>(d_in, d_out, (char*)d_ws, stream);
  else
    run_pipe<u16>(d_in, d_out, (char*)d_ws, stream);
}

// Round 5
// 607.956 us; speedup vs baseline: 1.6314x; 1.1003x over previous
//
#include <hip/hip_runtime.h>
#include <stdint.h>

typedef unsigned short u16;

static const int N_NODES = 131072;   // B*T*NN = 128*128*8
static const int N_EDGES = 1048576;

__device__ __forceinline__ float u2f(u16 u){
  union{uint32_t i; float f;} w; w.i = ((uint32_t)u)<<16; return w.f;
}
__device__ __forceinline__ u16 f2u(float f){
  union{float f; uint32_t u;} v; v.f=f;
  uint32_t u=v.u;
  u += 0x7fff + ((u>>16)&1);   // round-to-nearest-even
  return (u16)(u>>16);
}
// internal-buffer typed access
__device__ __forceinline__ float ldv(const float* p, int i){ return p[i]; }
__device__ __forceinline__ float ldv(const u16* p, int i){ return u2f(p[i]); }
__device__ __forceinline__ void stv(float* p, int i, float v){ p[i]=v; }
__device__ __forceinline__ void stv(u16* p, int i, float v){ p[i]=f2u(v); }
// external-input access, runtime dtype
__device__ __forceinline__ float ldmix(const void* p, int i, int isbf){
  return isbf ? u2f(((const u16*)p)[i]) : ((const float*)p)[i];
}

// ---------------- dtype detection ----------------
__global__ void k_detect(const uint32_t* __restrict__ x, int* __restrict__ flag){
  if (threadIdx.x==0 && blockIdx.x==0){
    int cnt=0;
    for (int i=0;i<256;i++){
      uint32_t e=(x[i]>>7)&0xFFu;
      if (e>=0x6Fu && e<=0x85u) cnt++;
    }
    *flag = (cnt>=128) ? 1 : 0;
  }
}

// ---------------- graph prep ----------------
__global__ __launch_bounds__(256) void k_count(const int* __restrict__ dst, int* __restrict__ deg){
  int e = blockIdx.x*256 + threadIdx.x;
  atomicAdd(&deg[dst[e] & (N_NODES-1)], 1);
}
__global__ __launch_bounds__(256) void k_dinv(const int* __restrict__ deg, float* __restrict__ dinv){
  int n = blockIdx.x*256 + threadIdx.x;
  dinv[n] = rsqrtf((float)deg[n] + 1.0f);   // +1 self loop
}
__global__ __launch_bounds__(256) void k_scan1(const int* __restrict__ deg, int* __restrict__ offs,
                                               int* __restrict__ bsum){
  __shared__ int sh[256];
  int t = threadIdx.x, i = blockIdx.x*256 + t;
  int v = deg[i]; sh[t] = v; __syncthreads();
  for (int d=1; d<256; d<<=1){
    int o = (t>=d) ? sh[t-d] : 0; __syncthreads();
    sh[t] += o; __syncthreads();
  }
  offs[i] = sh[t] - v;
  if (t==255) bsum[blockIdx.x] = sh[t];
}
__global__ __launch_bounds__(512) void k_scan2(int* __restrict__ bsum){
  __shared__ int sh[512];
  int t = threadIdx.x;
  int v = bsum[t]; sh[t] = v; __syncthreads();
  for (int d=1; d<512; d<<=1){
    int o = (t>=d) ? sh[t-d] : 0; __syncthreads();
    sh[t] += o; __syncthreads();
  }
  bsum[t] = sh[t] - v;
}
__global__ __launch_bounds__(256) void k_scan3(int* __restrict__ offs, const int* __restrict__ bsum){
  int i = blockIdx.x*256 + threadIdx.x;
  offs[i] += bsum[blockIdx.x];
}
__global__ __launch_bounds__(256) void k_fill(const int* __restrict__ src, const int* __restrict__ dst,
                                              const int* __restrict__ offs, int* __restrict__ cur,
                                              int* __restrict__ adj){
  int e = blockIdx.x*256 + threadIdx.x;
  int d = dst[e] & (N_NODES-1);
  int p = atomicAdd(&cur[d], 1);
  int idx = offs[d] + p;
  if (idx >= 0 && idx < N_EDGES) adj[idx] = src[e] & (N_NODES-1);
}

// ---- prescale external input by dinv: Xs[n,c] = dinv[n]*x[n,c]  (F=32) ----
template<typename T>
__global__ __launch_bounds__(256) void k_prescale(const void* __restrict__ X, const int* __restrict__ flag,
                                                  const float* __restrict__ dinv, T* __restrict__ out){
  int isbf = *flag;
  int i = blockIdx.x*256 + threadIdx.x;
  int n = i >> 5;
  stv(out, i, dinv[n]*ldmix(X, i, isbf));
}

// ---- GCN aggregation on prescaled rows: out[n] = dinv[n]*(Xs[n] + sum_in Xs[s]) ----
// batch-8 gather: 8 outstanding row loads per wave to hide LLC latency.
template<int F, typename T>
__global__ __launch_bounds__(256) void k_aggp(const T* __restrict__ Xs,
                                              const int* __restrict__ adj, const int* __restrict__ offs,
                                              const int* __restrict__ deg, const float* __restrict__ dinv,
                                              T* __restrict__ out){
  constexpr int LOG = (F==64) ? 6 : 5;
  int c = threadIdx.x & (F-1);
  int slot = threadIdx.x >> LOG;
  int n = blockIdx.x*(256>>LOG) + slot;
  int o = offs[n] & (N_EDGES-1);
  int cnt = min(deg[n], 8192);
  float acc = ldv(Xs, (n<<LOG)+c);            // prescaled self term
  int e = 0;
  for (; e+8 <= cnt; e += 8){
    int s0 = adj[o+e+0] & (N_NODES-1);
    int s1 = adj[o+e+1] & (N_NODES-1);
    int s2 = adj[o+e+2] & (N_NODES-1);
    int s3 = adj[o+e+3] & (N_NODES-1);
    int s4 = adj[o+e+4] & (N_NODES-1);
    int s5 = adj[o+e+5] & (N_NODES-1);
    int s6 = adj[o+e+6] & (N_NODES-1);
    int s7 = adj[o+e+7] & (N_NODES-1);
    float x0 = ldv(Xs, (s0<<LOG)+c);
    float x1 = ldv(Xs, (s1<<LOG)+c);
    float x2 = ldv(Xs, (s2<<LOG)+c);
    float x3 = ldv(Xs, (s3<<LOG)+c);
    float x4 = ldv(Xs, (s4<<LOG)+c);
    float x5 = ldv(Xs, (s5<<LOG)+c);
    float x6 = ldv(Xs, (s6<<LOG)+c);
    float x7 = ldv(Xs, (s7<<LOG)+c);
    acc += ((x0+x1)+(x2+x3)) + ((x4+x5)+(x6+x7));
  }
  if (e + 4 <= cnt){
    int s0 = adj[o+e+0] & (N_NODES-1);
    int s1 = adj[o+e+1] & (N_NODES-1);
    int s2 = adj[o+e+2] & (N_NODES-1);
    int s3 = adj[o+e+3] & (N_NODES-1);
    float x0 = ldv(Xs, (s0<<LOG)+c);
    float x1 = ldv(Xs, (s1<<LOG)+c);
    float x2 = ldv(Xs, (s2<<LOG)+c);
    float x3 = ldv(Xs, (s3<<LOG)+c);
    acc += (x0+x1)+(x2+x3);
    e += 4;
  }
  for (; e<cnt; e++){
    int s = adj[o+e] & (N_NODES-1);
    acc += ldv(Xs, (s<<LOG)+c);
  }
  stv(out, (n<<LOG)+c, dinv[n]*acc);
}

// ---- combine GCN weight with temporal-conv weight ----
template<int Kin>
__global__ __launch_bounds__(64) void k_wcomb(const void* __restrict__ gW, const void* __restrict__ gb,
                                              const void* __restrict__ tw, const int* __restrict__ flag,
                                              float* __restrict__ W2, float* __restrict__ braw){
  int isbf = *flag;
  int r = blockIdx.x;
  int co = threadIdx.x;
  if (r < 3*Kin){
    int k = r / Kin, j = r % Kin;
    float acc = 0.f;
    for (int c=0; c<64; c++)
      acc += ldmix(gW, j*64+c, isbf) * ldmix(tw, co*192 + c*3 + k, isbf);
    W2[r*64 + co] = acc;
  } else {
    int k = r - 3*Kin;
    float acc = 0.f;
    for (int c=0; c<64; c++)
      acc += ldmix(gb, c, isbf) * ldmix(tw, co*192 + c*3 + k, isbf);
    braw[k*64 + co] = acc;
  }
}

// ---- fused linear+temporal-conv as GEMM ----
template<int Kin, typename T>
__global__ __launch_bounds__(256) void k_tconv2(const T* __restrict__ A, const float* __restrict__ W2,
                                                const float* __restrict__ braw, const void* __restrict__ tb,
                                                const int* __restrict__ flag, T* __restrict__ out){
  __shared__ float At[Kin][132];        // s = t+1 in [0,129]
  __shared__ float Ws[3*Kin][32];
  int isbf = *flag;
  int bid = blockIdx.x;
  int half = bid & 1, g = bid >> 1;
  int b = g >> 3, v = g & 7;
  const int tid = threadIdx.x;

  for (int i = tid; i < 3*Kin*32; i += 256){
    int r = i >> 5, c = i & 31;
    Ws[r][c] = W2[r*64 + half*32 + c];
  }
  constexpr int SH = (Kin == 64) ? 6 : 5;
  for (int i = tid; i < 130*Kin; i += 256){
    int s = i >> SH, j = i & (Kin-1);
    int t = s - 1;
    float val = 0.f;
    if (t >= 0 && t < 128) val = ldv(A, (((b*128+t)*8+v) << SH) + j);
    At[j][s] = val;
  }
  __syncthreads();

  int tgroup = tid >> 3;
  int cog    = tid & 7;
  int t0 = tgroup << 2;
  int co0 = half*32 + (cog << 2);

  float acc[4][4];
  #pragma unroll
  for (int cc=0; cc<4; cc++){
    float b0 = braw[co0+cc], b1 = braw[64+co0+cc], b2 = braw[128+co0+cc];
    float ball = ldmix(tb, co0+cc, isbf) + b0 + b1 + b2;
    #pragma unroll
    for (int tt=0; tt<4; tt++){
      int t = t0 + tt;
      float bv = ball;
      if (t == 0)   bv -= b0;
      if (t == 127) bv -= b2;
      acc[tt][cc] = bv;
    }
  }

  for (int j = 0; j < Kin; j++){
    float4 a4 = *(const float4*)&At[j][t0];
    float2 a2 = *(const float2*)&At[j][t0+4];
    float a6[6] = {a4.x, a4.y, a4.z, a4.w, a2.x, a2.y};
    #pragma unroll
    for (int k=0; k<3; k++){
      float4 w = *(const float4*)&Ws[k*Kin + j][cog << 2];
      float wv[4] = {w.x, w.y, w.z, w.w};
      #pragma unroll
      for (int tt=0; tt<4; tt++){
        float av = a6[tt + k];
        #pragma unroll
        for (int cc=0; cc<4; cc++) acc[tt][cc] += av * wv[cc];
      }
    }
  }

  #pragma unroll
  for (int tt=0; tt<4; tt++){
    int t = t0 + tt;
    int base = (((b*128+t)*8+v) << 6) + co0;
    #pragma unroll
    for (int cc=0; cc<4; cc++) stv(out, base + cc, acc[tt][cc]);
  }
}

// ---- BN stats: per-channel sum / sumsq ----
template<typename T>
__global__ __launch_bounds__(256) void k_stats(const T* __restrict__ X, float* __restrict__ stats){
  int co = threadIdx.x & 63, g = threadIdx.x >> 6;
  float s = 0.f, s2 = 0.f;
  for (int row = blockIdx.x*4 + g; row < N_NODES; row += gridDim.x*4){
    float v = ldv(X, (row<<6) + co);
    s += v; s2 += v*v;
  }
  __shared__ float sh[512];
  sh[threadIdx.x] = s; sh[256+threadIdx.x] = s2;
  __syncthreads();
  if (g == 0){
    s  = sh[co] + sh[64+co] + sh[128+co] + sh[192+co];
    s2 = sh[256+co] + sh[320+co] + sh[384+co] + sh[448+co];
    atomicAdd(&stats[co], s);
    atomicAdd(&stats[64+co], s2);
  }
}

// ---- BN-apply + ReLU + 1x1 conv + tanh (+ optional dinv-prescale) + scrambled view write ----
template<typename T>
__global__ __launch_bounds__(256) void k_bnfuse(const T* __restrict__ X, const float* __restrict__ stats,
                                                const void* __restrict__ gam, const void* __restrict__ bet,
                                                const void* __restrict__ ow, const void* __restrict__ ob,
                                                const int* __restrict__ flag, const float* __restrict__ presc,
                                                T* __restrict__ out){
  __shared__ float y_s[64*65];
  __shared__ float ow_s[64*64];    // [co][ci]
  __shared__ float kk[64], bsh[64];
  int isbf = *flag;
  int bid = blockIdx.x;
  int b = bid>>4, rem = bid&15, v = rem>>1, thi = rem&1;
  int t0 = thi<<6;
  const float invM = 1.0f/131072.0f;
  if (threadIdx.x < 64){
    int ci = threadIdx.x;
    float mu = stats[ci]*invM;
    float var = stats[64+ci]*invM - mu*mu;
    float rs = rsqrtf(fmaxf(var, 0.f) + 1e-5f);
    float kv = rs*ldmix(gam, ci, isbf);
    kk[ci] = kv;
    bsh[ci] = ldmix(bet, ci, isbf) - mu*kv;
  }
  for (int i=threadIdx.x; i<4096; i+=256) ow_s[i] = ldmix(ow, i, isbf);
  __syncthreads();
  for (int i=threadIdx.x; i<4096; i+=256){
    int tl = i>>6, ci = i&63;
    int t = t0 + tl;
    float val = ldv(X, (((b*128+t)*8+v)<<6) + ci);
    val = val*kk[ci] + bsh[ci];
    y_s[tl*65 + ci] = fmaxf(val, 0.f);
  }
  __syncthreads();
  int l = threadIdx.x & 63, wg = threadIdx.x >> 6;
  float acc[16];
  #pragma unroll
  for (int c8=0; c8<16; c8++) acc[c8] = ldmix(ob, wg*16 + c8, isbf);
  for (int ci=0; ci<64; ci++){
    float yv = y_s[l*65 + ci];
    #pragma unroll
    for (int c8=0; c8<16; c8++) acc[c8] += ow_s[((wg*16+c8)<<6) + ci]*yv;
  }
  #pragma unroll
  for (int c8=0; c8<16; c8++){
    int co = wg*16 + c8;
    float z = tanhf(acc[c8]);
    int r = (b<<10) + (co<<4) + (v<<1) + thi;
    if (presc) z *= presc[r];     // lane-uniform broadcast
    stv(out, (r<<6) + l, z);
  }
}

// ---- final: out[b,v] = mean_{t,f}( x3 @ reg_w + reg_b ) ----
template<typename T>
__global__ __launch_bounds__(256) void k_final(const T* __restrict__ X, const void* __restrict__ rw,
                                               const void* __restrict__ rb, const int* __restrict__ flag,
                                               void* __restrict__ out){
  __shared__ float rw_s[64];
  __shared__ float rbs_s;
  __shared__ float wred[4];
  int isbf = *flag;
  int bid = blockIdx.x;
  int b = bid>>3, v = bid&7;
  if (threadIdx.x < 64){
    float s = 0.f;
    #pragma unroll
    for (int f=0; f<8; f++) s += ldmix(rw, threadIdx.x*8 + f, isbf);
    rw_s[threadIdx.x] = s;
  }
  if (threadIdx.x == 0){
    float s = 0.f;
    for (int f=0; f<8; f++) s += ldmix(rb, f, isbf);
    rbs_s = s;
  }
  __syncthreads();
  float acc = 0.f;
  for (int i=threadIdx.x; i<128*64; i+=256){
    int t = i>>6, j = i&63;
    acc += ldv(X, (((b*128+t)*8+v)<<6) + j) * rw_s[j];
  }
  for (int off=32; off; off>>=1) acc += __shfl_down(acc, off);
  if ((threadIdx.x & 63) == 0) wred[threadIdx.x>>6] = acc;
  __syncthreads();
  if (threadIdx.x == 0){
    float r = wred[0]+wred[1]+wred[2]+wred[3];
    float val = r*(1.0f/1024.0f) + rbs_s*0.125f;
    if (isbf) ((u16*)out)[bid] = f2u(val);
    else      ((float*)out)[bid] = val;
  }
}

// ---------------- host pipeline ----------------
template<typename T>
static void run_pipe(void* const* d_in, void* out, char* p, hipStream_t stream){
  auto alloc = [&](size_t bytes){ void* r = (void*)p; p += (bytes + 255) & ~(size_t)255; return r; };
  T*     A    = (T*)    alloc(sizeof(T)*(size_t)N_NODES*64);
  T*     B    = (T*)    alloc(sizeof(T)*(size_t)N_NODES*64);
  int*   deg  = (int*)  alloc(sizeof(int)*N_NODES);
  float* dinv = (float*)alloc(sizeof(float)*N_NODES);
  int*   offs = (int*)  alloc(sizeof(int)*N_NODES);
  int*   cur  = (int*)  alloc(sizeof(int)*N_NODES);
  int*   adj  = (int*)  alloc(sizeof(int)*N_EDGES);
  int*   bsum = (int*)  alloc(sizeof(int)*512);
  float* stats= (float*)alloc(sizeof(float)*128);
  int*   flag = (int*)  alloc(sizeof(int)*64);
  float* W2ws = (float*)alloc(sizeof(float)*192*64);
  float* braw = (float*)alloc(sizeof(float)*192);

  const void* x   = d_in[0];
  const int* edge = (const int*)d_in[1];
  const void* g1w = d_in[2];  const void* g1b = d_in[3];
  const void* t1w = d_in[4];  const void* t1b = d_in[5];
  const void* bn1g= d_in[6];  const void* bn1b= d_in[7];
  const void* o1w = d_in[8];  const void* o1b = d_in[9];
  const void* g2w = d_in[10]; const void* g2b = d_in[11];
  const void* t2w = d_in[12]; const void* t2b = d_in[13];
  const void* bn2g= d_in[14]; const void* bn2b= d_in[15];
  const void* o2w = d_in[16]; const void* o2b = d_in[17];
  const void* rw  = d_in[18]; const void* rb  = d_in[19];
  const int* src = edge;
  const int* dst = edge + N_EDGES;

  k_detect<<<1, 64, 0, stream>>>((const uint32_t*)x, flag);

  // graph prep
  hipMemsetAsync(deg, 0, sizeof(int)*N_NODES, stream);
  k_count<<<N_EDGES/256, 256, 0, stream>>>(dst, deg);
  k_dinv <<<N_NODES/256, 256, 0, stream>>>(deg, dinv);
  k_scan1<<<512, 256, 0, stream>>>(deg, offs, bsum);
  k_scan2<<<1, 512, 0, stream>>>(bsum);
  k_scan3<<<512, 256, 0, stream>>>(offs, bsum);
  hipMemsetAsync(cur, 0, sizeof(int)*N_NODES, stream);
  k_fill <<<N_EDGES/256, 256, 0, stream>>>(src, dst, offs, cur, adj);

  // ---- layer 1 ----
  k_prescale<T>  <<<N_NODES*32/256, 256, 0, stream>>>(x, flag, dinv, B);   // B = dinv*x  [N,32]
  k_aggp<32,T>   <<<N_NODES/8, 256, 0, stream>>>(B, adj, offs, deg, dinv, A);
  k_wcomb<32>    <<<3*32+3, 64, 0, stream>>>(g1w, g1b, t1w, flag, W2ws, braw);
  k_tconv2<32,T> <<<2048, 256, 0, stream>>>(A, W2ws, braw, t1b, flag, B);
  hipMemsetAsync(stats, 0, sizeof(float)*128, stream);
  k_stats<T>     <<<512, 256, 0, stream>>>(B, stats);
  k_bnfuse<T>    <<<2048, 256, 0, stream>>>(B, stats, bn1g, bn1b, o1w, o1b, flag, dinv, A);  // A prescaled

  // ---- layer 2 ----
  k_aggp<64,T>   <<<N_NODES/4, 256, 0, stream>>>(A, adj, offs, deg, dinv, B);
  k_wcomb<64>    <<<3*64+3, 64, 0, stream>>>(g2w, g2b, t2w, flag, W2ws, braw);
  k_tconv2<64,T> <<<2048, 256, 0, stream>>>(B, W2ws, braw, t2b, flag, A);
  hipMemsetAsync(stats, 0, sizeof(float)*128, stream);
  k_stats<T>     <<<512, 256, 0, stream>>>(A, stats);
  k_bnfuse<T>    <<<2048, 256, 0, stream>>>(A, stats, bn2g, bn2b, o2w, o2b, flag, (const float*)nullptr, B);

  // ---- regression + mean ----
  k_final<T><<<1024, 256, 0, stream>>>(B, rw, rb, flag, out);
}

extern "C" void kernel_launch(void* const* d_in, const int* in_sizes, int n_in,
                              void* d_out, int out_size, void* d_ws, size_t ws_size,
                              hipStream_t stream){
  (void)in_sizes; (void)n_in; (void)out_size;
  const size_t csr_bytes = 4*sizeof(int)*(size_t)N_NODES + sizeof(int)*(size_t)N_EDGES + 131072;
  const size_t need_f32  = 2*sizeof(float)*(size_t)N_NODES*64 + csr_bytes;   // ~73.5 MB
  if (ws_size >= need_f32)
    run_pipe<float>(d_in, d_out, (char*)d_ws, stream);
  else
    run_pipe<u16>(d_in, d_out, (char*)d_ws, stream);
}

// Round 6
// 573.251 us; speedup vs baseline: 1.7301x; 1.0605x over previous
//
#include <hip/hip_runtime.h>
#include <stdint.h>

typedef unsigned short u16;

static const int N_NODES = 131072;   // B*T*NN = 128*128*8
static const int N_EDGES = 1048576;

__device__ __forceinline__ float u2f(u16 u){
  union{uint32_t i; float f;} w; w.i = ((uint32_t)u)<<16; return w.f;
}
__device__ __forceinline__ u16 f2u(float f){
  union{float f; uint32_t u;} v; v.f=f;
  uint32_t u=v.u;
  u += 0x7fff + ((u>>16)&1);   // round-to-nearest-even
  return (u16)(u>>16);
}
// internal-buffer typed access
__device__ __forceinline__ float ldv(const float* p, int i){ return p[i]; }
__device__ __forceinline__ float ldv(const u16* p, int i){ return u2f(p[i]); }
__device__ __forceinline__ void stv(float* p, int i, float v){ p[i]=v; }
__device__ __forceinline__ void stv(u16* p, int i, float v){ p[i]=f2u(v); }
__device__ __forceinline__ float4 ld4(const float* p, int i){ return *(const float4*)(p+i); }
__device__ __forceinline__ float4 ld4(const u16* p, int i){
  ushort4 u = *(const ushort4*)(p+i);
  return make_float4(u2f(u.x), u2f(u.y), u2f(u.z), u2f(u.w));
}
__device__ __forceinline__ void st4(float* p, int i, float4 v){ *(float4*)(p+i) = v; }
__device__ __forceinline__ void st4(u16* p, int i, float4 v){
  p[i]=f2u(v.x); p[i+1]=f2u(v.y); p[i+2]=f2u(v.z); p[i+3]=f2u(v.w);
}
// external-input access, runtime dtype
__device__ __forceinline__ float ldmix(const void* p, int i, int isbf){
  return isbf ? u2f(((const u16*)p)[i]) : ((const float*)p)[i];
}
__device__ __forceinline__ float4 ld4mix(const void* p, int i, int isbf){
  if (isbf){ return ld4((const u16*)p, i); }
  return ld4((const float*)p, i);
}

// ---------------- dtype detection ----------------
__global__ void k_detect(const uint32_t* __restrict__ x, int* __restrict__ flag){
  if (threadIdx.x==0 && blockIdx.x==0){
    int cnt=0;
    for (int i=0;i<256;i++){
      uint32_t e=(x[i]>>7)&0xFFu;
      if (e>=0x6Fu && e<=0x85u) cnt++;
    }
    *flag = (cnt>=128) ? 1 : 0;
  }
}

// ---------------- graph prep ----------------
__global__ __launch_bounds__(256) void k_count(const int* __restrict__ dst, int* __restrict__ deg){
  int e = blockIdx.x*256 + threadIdx.x;
  atomicAdd(&deg[dst[e] & (N_NODES-1)], 1);
}
__global__ __launch_bounds__(256) void k_dinv(const int* __restrict__ deg, float* __restrict__ dinv){
  int n = blockIdx.x*256 + threadIdx.x;
  dinv[n] = rsqrtf((float)deg[n] + 1.0f);   // +1 self loop
}
__global__ __launch_bounds__(256) void k_scan1(const int* __restrict__ deg, int* __restrict__ offs,
                                               int* __restrict__ bsum){
  __shared__ int sh[256];
  int t = threadIdx.x, i = blockIdx.x*256 + t;
  int v = deg[i]; sh[t] = v; __syncthreads();
  for (int d=1; d<256; d<<=1){
    int o = (t>=d) ? sh[t-d] : 0; __syncthreads();
    sh[t] += o; __syncthreads();
  }
  offs[i] = sh[t] - v;
  if (t==255) bsum[blockIdx.x] = sh[t];
}
__global__ __launch_bounds__(512) void k_scan2(int* __restrict__ bsum){
  __shared__ int sh[512];
  int t = threadIdx.x;
  int v = bsum[t]; sh[t] = v; __syncthreads();
  for (int d=1; d<512; d<<=1){
    int o = (t>=d) ? sh[t-d] : 0; __syncthreads();
    sh[t] += o; __syncthreads();
  }
  bsum[t] = sh[t] - v;
}
__global__ __launch_bounds__(256) void k_scan3(int* __restrict__ offs, const int* __restrict__ bsum){
  int i = blockIdx.x*256 + threadIdx.x;
  offs[i] += bsum[blockIdx.x];
}
__global__ __launch_bounds__(256) void k_fill(const int* __restrict__ src, const int* __restrict__ dst,
                                              const int* __restrict__ offs, int* __restrict__ cur,
                                              int* __restrict__ adj){
  int e = blockIdx.x*256 + threadIdx.x;
  int d = dst[e] & (N_NODES-1);
  int p = atomicAdd(&cur[d], 1);
  int idx = offs[d] + p;
  if (idx >= 0 && idx < N_EDGES) adj[idx] = src[e] & (N_NODES-1);
}

// ---- prescale external input by dinv: Xs[n,c] = dinv[n]*x[n,c]  (F=32) ----
template<typename T>
__global__ __launch_bounds__(256) void k_prescale(const void* __restrict__ X, const int* __restrict__ flag,
                                                  const float* __restrict__ dinv, T* __restrict__ out){
  int isbf = *flag;
  int i = blockIdx.x*256 + threadIdx.x;
  int n = i >> 5;
  stv(out, i, dinv[n]*ldmix(X, i, isbf));
}

// ---- GCN aggregation on prescaled rows: out[n] = dinv[n]*(Xs[n] + sum_in Xs[s]) ----
template<int F, typename T>
__global__ __launch_bounds__(256) void k_aggp(const T* __restrict__ Xs,
                                              const int* __restrict__ adj, const int* __restrict__ offs,
                                              const int* __restrict__ deg, const float* __restrict__ dinv,
                                              T* __restrict__ out){
  constexpr int LOG = (F==64) ? 6 : 5;
  int c = threadIdx.x & (F-1);
  int slot = threadIdx.x >> LOG;
  int n = blockIdx.x*(256>>LOG) + slot;
  int o = offs[n] & (N_EDGES-1);
  int cnt = min(deg[n], 8192);
  float acc = ldv(Xs, (n<<LOG)+c);            // prescaled self term
  int e = 0;
  for (; e+8 <= cnt; e += 8){
    int s0 = adj[o+e+0] & (N_NODES-1);
    int s1 = adj[o+e+1] & (N_NODES-1);
    int s2 = adj[o+e+2] & (N_NODES-1);
    int s3 = adj[o+e+3] & (N_NODES-1);
    int s4 = adj[o+e+4] & (N_NODES-1);
    int s5 = adj[o+e+5] & (N_NODES-1);
    int s6 = adj[o+e+6] & (N_NODES-1);
    int s7 = adj[o+e+7] & (N_NODES-1);
    float x0 = ldv(Xs, (s0<<LOG)+c);
    float x1 = ldv(Xs, (s1<<LOG)+c);
    float x2 = ldv(Xs, (s2<<LOG)+c);
    float x3 = ldv(Xs, (s3<<LOG)+c);
    float x4 = ldv(Xs, (s4<<LOG)+c);
    float x5 = ldv(Xs, (s5<<LOG)+c);
    float x6 = ldv(Xs, (s6<<LOG)+c);
    float x7 = ldv(Xs, (s7<<LOG)+c);
    acc += ((x0+x1)+(x2+x3)) + ((x4+x5)+(x6+x7));
  }
  if (e + 4 <= cnt){
    int s0 = adj[o+e+0] & (N_NODES-1);
    int s1 = adj[o+e+1] & (N_NODES-1);
    int s2 = adj[o+e+2] & (N_NODES-1);
    int s3 = adj[o+e+3] & (N_NODES-1);
    float x0 = ldv(Xs, (s0<<LOG)+c);
    float x1 = ldv(Xs, (s1<<LOG)+c);
    float x2 = ldv(Xs, (s2<<LOG)+c);
    float x3 = ldv(Xs, (s3<<LOG)+c);
    acc += (x0+x1)+(x2+x3);
    e += 4;
  }
  for (; e<cnt; e++){
    int s = adj[o+e] & (N_NODES-1);
    acc += ldv(Xs, (s<<LOG)+c);
  }
  stv(out, (n<<LOG)+c, dinv[n]*acc);
}

// ---- combine GCN weight with temporal-conv weight ----
template<int Kin>
__global__ __launch_bounds__(64) void k_wcomb(const void* __restrict__ gW, const void* __restrict__ gb,
                                              const void* __restrict__ tw, const int* __restrict__ flag,
                                              float* __restrict__ W2, float* __restrict__ braw){
  int isbf = *flag;
  int r = blockIdx.x;
  int co = threadIdx.x;
  if (r < 3*Kin){
    int k = r / Kin, j = r % Kin;
    float acc = 0.f;
    for (int c=0; c<64; c++)
      acc += ldmix(gW, j*64+c, isbf) * ldmix(tw, co*192 + c*3 + k, isbf);
    W2[r*64 + co] = acc;
  } else {
    int k = r - 3*Kin;
    float acc = 0.f;
    for (int c=0; c<64; c++)
      acc += ldmix(gb, c, isbf) * ldmix(tw, co*192 + c*3 + k, isbf);
    braw[k*64 + co] = acc;
  }
}

// ---- fused linear+temporal-conv, register-tiled GEMM ----
// block = (b, v, co-half): 128 threads, thread tile 8t x 4co over a 128t x 32co output.
template<int Kin, typename T>
__global__ __launch_bounds__(128) void k_tconv2(const T* __restrict__ A, const float* __restrict__ W2,
                                                const float* __restrict__ braw, const void* __restrict__ tb,
                                                const int* __restrict__ flag, T* __restrict__ out){
  __shared__ float At[Kin][132];        // col s = t+1 in [0,129]
  __shared__ float Ws[3*Kin][36];       // 36-stride: conflict-free b128 reads
  int isbf = *flag;
  int bid = blockIdx.x;
  int half = bid & 1, g = bid >> 1;
  int b = g >> 3, v = g & 7;
  const int tid = threadIdx.x;

  // stage weights (vectorized)
  for (int u = tid; u < 3*Kin*8; u += 128){
    int r = u >> 3, cq = (u & 7) << 2;
    *(float4*)&Ws[r][cq] = *(const float4*)&W2[r*64 + (half<<5) + cq];
  }
  // stage A transposed (float4 global reads, scalar LDS writes)
  constexpr int SH  = (Kin == 64) ? 6 : 5;
  constexpr int JQ  = Kin/4;
  constexpr int JQL = (Kin == 64) ? 4 : 3;
  for (int u = tid; u < 130*JQ; u += 128){
    int s = u >> JQL, j0 = (u & (JQ-1)) << 2;
    int t = s - 1;
    float4 a = make_float4(0.f,0.f,0.f,0.f);
    if (t >= 0 && t < 128) a = ld4(A, (((b*128+t)*8+v) << SH) + j0);
    At[j0  ][s] = a.x;
    At[j0+1][s] = a.y;
    At[j0+2][s] = a.z;
    At[j0+3][s] = a.w;
  }
  __syncthreads();

  int tg = tid >> 3, cog = tid & 7;
  int t0 = tg << 3;
  int co0 = (half << 5) + (cog << 2);

  float acc[8][4];
  #pragma unroll
  for (int cc=0; cc<4; cc++){
    float b0 = braw[co0+cc], b1 = braw[64+co0+cc], b2 = braw[128+co0+cc];
    float ball = ldmix(tb, co0+cc, isbf) + b0 + b1 + b2;
    #pragma unroll
    for (int tt=0; tt<8; tt++){
      int t = t0 + tt;
      float bv = ball;
      if (t == 0)   bv -= b0;
      if (t == 127) bv -= b2;
      acc[tt][cc] = bv;
    }
  }

  for (int j = 0; j < Kin; j++){
    const float* row = &At[j][t0];
    float4 p = *(const float4*)&row[0];
    float4 q = *(const float4*)&row[4];
    float2 r2 = *(const float2*)&row[8];
    float a10[10] = {p.x,p.y,p.z,p.w,q.x,q.y,q.z,q.w,r2.x,r2.y};
    #pragma unroll
    for (int k=0; k<3; k++){
      float4 w = *(const float4*)&Ws[k*Kin + j][cog << 2];
      float wv[4] = {w.x, w.y, w.z, w.w};
      #pragma unroll
      for (int tt=0; tt<8; tt++){
        float av = a10[tt + k];
        #pragma unroll
        for (int cc=0; cc<4; cc++) acc[tt][cc] += av * wv[cc];
      }
    }
  }

  #pragma unroll
  for (int tt=0; tt<8; tt++){
    int t = t0 + tt;
    int base = (((b*128+t)*8+v) << 6) + co0;
    st4(out, base, make_float4(acc[tt][0], acc[tt][1], acc[tt][2], acc[tt][3]));
  }
}

// ---- BN stats: per-channel sum / sumsq (float4) ----
template<typename T>
__global__ __launch_bounds__(256) void k_stats(const T* __restrict__ X, float* __restrict__ stats){
  int cq = (threadIdx.x & 15) << 2;   // co-quad
  int g  = threadIdx.x >> 4;          // 16 row-groups
  float4 s  = make_float4(0.f,0.f,0.f,0.f);
  float4 s2 = make_float4(0.f,0.f,0.f,0.f);
  for (int row = blockIdx.x*16 + g; row < N_NODES; row += gridDim.x*16){
    float4 v = ld4(X, (row<<6) + cq);
    s.x += v.x; s.y += v.y; s.z += v.z; s.w += v.w;
    s2.x += v.x*v.x; s2.y += v.y*v.y; s2.z += v.z*v.z; s2.w += v.w*v.w;
  }
  __shared__ float sh[16][64], sh2[16][64];
  *(float4*)&sh[g][cq]  = s;
  *(float4*)&sh2[g][cq] = s2;
  __syncthreads();
  if (threadIdx.x < 64){
    int co = threadIdx.x;
    float a = 0.f, a2 = 0.f;
    #pragma unroll
    for (int gg=0; gg<16; gg++){ a += sh[gg][co]; a2 += sh2[gg][co]; }
    atomicAdd(&stats[co], a);
    atomicAdd(&stats[64+co], a2);
  }
}

// ---- BN-apply + ReLU + 1x1 conv + tanh (+ optional dinv-prescale) + scrambled view write ----
template<typename T>
__global__ __launch_bounds__(256) void k_bnfuse(const T* __restrict__ X, const float* __restrict__ stats,
                                                const void* __restrict__ gam, const void* __restrict__ bet,
                                                const void* __restrict__ ow, const void* __restrict__ ob,
                                                const int* __restrict__ flag, const float* __restrict__ presc,
                                                T* __restrict__ out){
  __shared__ float y_s[64*68];     // stride 68: 16B-aligned float4 per ci-quad
  __shared__ float ow_s[64*64];    // [co][ci]
  __shared__ float kk[64], bsh[64];
  int isbf = *flag;
  int bid = blockIdx.x;
  int b = bid>>4, rem = bid&15, v = rem>>1, thi = rem&1;
  int t0 = thi<<6;
  const float invM = 1.0f/131072.0f;
  if (threadIdx.x < 64){
    int ci = threadIdx.x;
    float mu = stats[ci]*invM;
    float var = stats[64+ci]*invM - mu*mu;
    float rs = rsqrtf(fmaxf(var, 0.f) + 1e-5f);
    float kv = rs*ldmix(gam, ci, isbf);
    kk[ci] = kv;
    bsh[ci] = ldmix(bet, ci, isbf) - mu*kv;
  }
  for (int u=threadIdx.x; u<1024; u+=256){
    int r = u>>4, cq = (u&15)<<2;
    *(float4*)&ow_s[(r<<6)+cq] = ld4mix(ow, (r<<6)+cq, isbf);
  }
  __syncthreads();
  for (int u=threadIdx.x; u<1024; u+=256){
    int tl = u>>4, cq = (u&15)<<2;
    int t = t0 + tl;
    float4 val = ld4(X, (((b*128+t)*8+v)<<6) + cq);
    float4 kq = *(const float4*)&kk[cq];
    float4 bq = *(const float4*)&bsh[cq];
    val.x = fmaxf(val.x*kq.x + bq.x, 0.f);
    val.y = fmaxf(val.y*kq.y + bq.y, 0.f);
    val.z = fmaxf(val.z*kq.z + bq.z, 0.f);
    val.w = fmaxf(val.w*kq.w + bq.w, 0.f);
    *(float4*)&y_s[tl*68 + cq] = val;
  }
  __syncthreads();
  int l = threadIdx.x & 63, wg = threadIdx.x >> 6;
  float acc[16];
  #pragma unroll
  for (int c8=0; c8<16; c8++) acc[c8] = ldmix(ob, wg*16 + c8, isbf);
  for (int ci=0; ci<64; ci+=4){
    float4 y4 = *(const float4*)&y_s[l*68 + ci];
    #pragma unroll
    for (int c8=0; c8<16; c8++){
      float4 w4 = *(const float4*)&ow_s[((wg*16+c8)<<6) + ci];
      acc[c8] += y4.x*w4.x + y4.y*w4.y + y4.z*w4.z + y4.w*w4.w;
    }
  }
  #pragma unroll
  for (int c8=0; c8<16; c8++){
    int co = wg*16 + c8;
    float z = tanhf(acc[c8]);
    int r = (b<<10) + (co<<4) + (v<<1) + thi;
    if (presc) z *= presc[r];     // lane-uniform broadcast
    stv(out, (r<<6) + l, z);
  }
}

// ---- final: out[b,v] = mean_{t,f}( x3 @ reg_w + reg_b ) ----
template<typename T>
__global__ __launch_bounds__(256) void k_final(const T* __restrict__ X, const void* __restrict__ rw,
                                               const void* __restrict__ rb, const int* __restrict__ flag,
                                               void* __restrict__ out){
  __shared__ float rw_s[64];
  __shared__ float rbs_s;
  __shared__ float wred[4];
  int isbf = *flag;
  int bid = blockIdx.x;
  int b = bid>>3, v = bid&7;
  if (threadIdx.x < 64){
    float s = 0.f;
    #pragma unroll
    for (int f=0; f<8; f++) s += ldmix(rw, threadIdx.x*8 + f, isbf);
    rw_s[threadIdx.x] = s;
  }
  if (threadIdx.x == 0){
    float s = 0.f;
    for (int f=0; f<8; f++) s += ldmix(rb, f, isbf);
    rbs_s = s;
  }
  __syncthreads();
  float acc = 0.f;
  for (int i=threadIdx.x; i<128*64; i+=256){
    int t = i>>6, j = i&63;
    acc += ldv(X, (((b*128+t)*8+v)<<6) + j) * rw_s[j];
  }
  for (int off=32; off; off>>=1) acc += __shfl_down(acc, off);
  if ((threadIdx.x & 63) == 0) wred[threadIdx.x>>6] = acc;
  __syncthreads();
  if (threadIdx.x == 0){
    float r = wred[0]+wred[1]+wred[2]+wred[3];
    float val = r*(1.0f/1024.0f) + rbs_s*0.125f;
    if (isbf) ((u16*)out)[bid] = f2u(val);
    else      ((float*)out)[bid] = val;
  }
}

// ---------------- host pipeline ----------------
template<typename T>
static void run_pipe(void* const* d_in, void* out, char* p, hipStream_t stream){
  auto alloc = [&](size_t bytes){ void* r = (void*)p; p += (bytes + 255) & ~(size_t)255; return r; };
  T*     A    = (T*)    alloc(sizeof(T)*(size_t)N_NODES*64);
  T*     B    = (T*)    alloc(sizeof(T)*(size_t)N_NODES*64);
  int*   deg  = (int*)  alloc(sizeof(int)*N_NODES);
  float* dinv = (float*)alloc(sizeof(float)*N_NODES);
  int*   offs = (int*)  alloc(sizeof(int)*N_NODES);
  int*   cur  = (int*)  alloc(sizeof(int)*N_NODES);
  int*   adj  = (int*)  alloc(sizeof(int)*N_EDGES);
  int*   bsum = (int*)  alloc(sizeof(int)*512);
  float* stats= (float*)alloc(sizeof(float)*128);
  int*   flag = (int*)  alloc(sizeof(int)*64);
  float* W2ws = (float*)alloc(sizeof(float)*192*64);
  float* braw = (float*)alloc(sizeof(float)*192);

  const void* x   = d_in[0];
  const int* edge = (const int*)d_in[1];
  const void* g1w = d_in[2];  const void* g1b = d_in[3];
  const void* t1w = d_in[4];  const void* t1b = d_in[5];
  const void* bn1g= d_in[6];  const void* bn1b= d_in[7];
  const void* o1w = d_in[8];  const void* o1b = d_in[9];
  const void* g2w = d_in[10]; const void* g2b = d_in[11];
  const void* t2w = d_in[12]; const void* t2b = d_in[13];
  const void* bn2g= d_in[14]; const void* bn2b= d_in[15];
  const void* o2w = d_in[16]; const void* o2b = d_in[17];
  const void* rw  = d_in[18]; const void* rb  = d_in[19];
  const int* src = edge;
  const int* dst = edge + N_EDGES;

  k_detect<<<1, 64, 0, stream>>>((const uint32_t*)x, flag);

  // graph prep
  hipMemsetAsync(deg, 0, sizeof(int)*N_NODES, stream);
  k_count<<<N_EDGES/256, 256, 0, stream>>>(dst, deg);
  k_dinv <<<N_NODES/256, 256, 0, stream>>>(deg, dinv);
  k_scan1<<<512, 256, 0, stream>>>(deg, offs, bsum);
  k_scan2<<<1, 512, 0, stream>>>(bsum);
  k_scan3<<<512, 256, 0, stream>>>(offs, bsum);
  hipMemsetAsync(cur, 0, sizeof(int)*N_NODES, stream);
  k_fill <<<N_EDGES/256, 256, 0, stream>>>(src, dst, offs, cur, adj);

  // ---- layer 1 ----
  k_prescale<T>  <<<N_NODES*32/256, 256, 0, stream>>>(x, flag, dinv, B);   // B = dinv*x  [N,32]
  k_aggp<32,T>   <<<N_NODES/8, 256, 0, stream>>>(B, adj, offs, deg, dinv, A);
  k_wcomb<32>    <<<3*32+3, 64, 0, stream>>>(g1w, g1b, t1w, flag, W2ws, braw);
  k_tconv2<32,T> <<<2048, 128, 0, stream>>>(A, W2ws, braw, t1b, flag, B);
  hipMemsetAsync(stats, 0, sizeof(float)*128, stream);
  k_stats<T>     <<<512, 256, 0, stream>>>(B, stats);
  k_bnfuse<T>    <<<2048, 256, 0, stream>>>(B, stats, bn1g, bn1b, o1w, o1b, flag, dinv, A);  // A prescaled

  // ---- layer 2 ----
  k_aggp<64,T>   <<<N_NODES/4, 256, 0, stream>>>(A, adj, offs, deg, dinv, B);
  k_wcomb<64>    <<<3*64+3, 64, 0, stream>>>(g2w, g2b, t2w, flag, W2ws, braw);
  k_tconv2<64,T> <<<2048, 128, 0, stream>>>(B, W2ws, braw, t2b, flag, A);
  hipMemsetAsync(stats, 0, sizeof(float)*128, stream);
  k_stats<T>     <<<512, 256, 0, stream>>>(A, stats);
  k_bnfuse<T>    <<<2048, 256, 0, stream>>>(A, stats, bn2g, bn2b, o2w, o2b, flag, (const float*)nullptr, B);

  // ---- regression + mean ----
  k_final<T><<<1024, 256, 0, stream>>>(B, rw, rb, flag, out);
}

extern "C" void kernel_launch(void* const* d_in, const int* in_sizes, int n_in,
                              void* d_out, int out_size, void* d_ws, size_t ws_size,
                              hipStream_t stream){
  (void)in_sizes; (void)n_in; (void)out_size;
  const size_t csr_bytes = 4*sizeof(int)*(size_t)N_NODES + sizeof(int)*(size_t)N_EDGES + 131072;
  const size_t need_f32  = 2*sizeof(float)*(size_t)N_NODES*64 + csr_bytes;   // ~73.5 MB
  if (ws_size >= need_f32)
    run_pipe<float>(d_in, d_out, (char*)d_ws, stream);
  else
    run_pipe<u16>(d_in, d_out, (char*)d_ws, stream);
}

// Round 7
// 508.785 us; speedup vs baseline: 1.9494x; 1.1267x over previous
//
#include <hip/hip_runtime.h>
#include <stdint.h>

typedef unsigned short u16;
typedef __attribute__((ext_vector_type(8))) short bf16x8;
typedef __attribute__((ext_vector_type(4))) float f32x4;

static const int N_NODES = 131072;   // B*T*NN = 128*128*8
static const int N_EDGES = 1048576;

__device__ __forceinline__ float u2f(u16 u){
  union{uint32_t i; float f;} w; w.i = ((uint32_t)u)<<16; return w.f;
}
__device__ __forceinline__ u16 f2u(float f){
  union{float f; uint32_t u;} v; v.f=f;
  uint32_t u=v.u;
  u += 0x7fff + ((u>>16)&1);   // round-to-nearest-even
  return (u16)(u>>16);
}
// internal-buffer typed access
__device__ __forceinline__ float ldv(const float* p, int i){ return p[i]; }
__device__ __forceinline__ float ldv(const u16* p, int i){ return u2f(p[i]); }
__device__ __forceinline__ void stv(float* p, int i, float v){ p[i]=v; }
__device__ __forceinline__ void stv(u16* p, int i, float v){ p[i]=f2u(v); }
__device__ __forceinline__ float4 ld4(const float* p, int i){ return *(const float4*)(p+i); }
__device__ __forceinline__ float4 ld4(const u16* p, int i){
  ushort4 u = *(const ushort4*)(p+i);
  return make_float4(u2f(u.x), u2f(u.y), u2f(u.z), u2f(u.w));
}
__device__ __forceinline__ void st4(float* p, int i, float4 v){ *(float4*)(p+i) = v; }
__device__ __forceinline__ void st4(u16* p, int i, float4 v){
  p[i]=f2u(v.x); p[i+1]=f2u(v.y); p[i+2]=f2u(v.z); p[i+3]=f2u(v.w);
}
// external-input access, runtime dtype
__device__ __forceinline__ float ldmix(const void* p, int i, int isbf){
  return isbf ? u2f(((const u16*)p)[i]) : ((const float*)p)[i];
}
__device__ __forceinline__ float4 ld4mix(const void* p, int i, int isbf){
  if (isbf){ return ld4((const u16*)p, i); }
  return ld4((const float*)p, i);
}

// ---------------- dtype detection ----------------
__global__ void k_detect(const uint32_t* __restrict__ x, int* __restrict__ flag){
  if (threadIdx.x==0 && blockIdx.x==0){
    int cnt=0;
    for (int i=0;i<256;i++){
      uint32_t e=(x[i]>>7)&0xFFu;
      if (e>=0x6Fu && e<=0x85u) cnt++;
    }
    *flag = (cnt>=128) ? 1 : 0;
  }
}

// ---------------- graph prep ----------------
__global__ __launch_bounds__(256) void k_count(const int* __restrict__ dst, int* __restrict__ deg){
  int e = blockIdx.x*256 + threadIdx.x;
  atomicAdd(&deg[dst[e] & (N_NODES-1)], 1);
}
__global__ __launch_bounds__(256) void k_dinv(const int* __restrict__ deg, float* __restrict__ dinv){
  int n = blockIdx.x*256 + threadIdx.x;
  dinv[n] = rsqrtf((float)deg[n] + 1.0f);   // +1 self loop
}
__global__ __launch_bounds__(256) void k_scan1(const int* __restrict__ deg, int* __restrict__ offs,
                                               int* __restrict__ bsum){
  __shared__ int sh[256];
  int t = threadIdx.x, i = blockIdx.x*256 + t;
  int v = deg[i]; sh[t] = v; __syncthreads();
  for (int d=1; d<256; d<<=1){
    int o = (t>=d) ? sh[t-d] : 0; __syncthreads();
    sh[t] += o; __syncthreads();
  }
  offs[i] = sh[t] - v;
  if (t==255) bsum[blockIdx.x] = sh[t];
}
__global__ __launch_bounds__(512) void k_scan2(int* __restrict__ bsum){
  __shared__ int sh[512];
  int t = threadIdx.x;
  int v = bsum[t]; sh[t] = v; __syncthreads();
  for (int d=1; d<512; d<<=1){
    int o = (t>=d) ? sh[t-d] : 0; __syncthreads();
    sh[t] += o; __syncthreads();
  }
  bsum[t] = sh[t] - v;
}
__global__ __launch_bounds__(256) void k_scan3(int* __restrict__ offs, const int* __restrict__ bsum){
  int i = blockIdx.x*256 + threadIdx.x;
  offs[i] += bsum[blockIdx.x];
}
__global__ __launch_bounds__(256) void k_fill(const int* __restrict__ src, const int* __restrict__ dst,
                                              const int* __restrict__ offs, int* __restrict__ cur,
                                              int* __restrict__ adj){
  int e = blockIdx.x*256 + threadIdx.x;
  int d = dst[e] & (N_NODES-1);
  int p = atomicAdd(&cur[d], 1);
  int idx = offs[d] + p;
  if (idx >= 0 && idx < N_EDGES) adj[idx] = src[e] & (N_NODES-1);
}

// ---- prescale external input by dinv: Xs[n,c] = dinv[n]*x[n,c]  (F=32) ----
template<typename T>
__global__ __launch_bounds__(256) void k_prescale(const void* __restrict__ X, const int* __restrict__ flag,
                                                  const float* __restrict__ dinv, T* __restrict__ out){
  int isbf = *flag;
  int i = blockIdx.x*256 + threadIdx.x;
  int n = i >> 5;
  stv(out, i, dinv[n]*ldmix(X, i, isbf));
}

// ---- GCN aggregation on prescaled rows: out[n] = dinv[n]*(Xs[n] + sum_in Xs[s]) ----
template<int F, typename T>
__global__ __launch_bounds__(256) void k_aggp(const T* __restrict__ Xs,
                                              const int* __restrict__ adj, const int* __restrict__ offs,
                                              const int* __restrict__ deg, const float* __restrict__ dinv,
                                              T* __restrict__ out){
  constexpr int LOG = (F==64) ? 6 : 5;
  int c = threadIdx.x & (F-1);
  int slot = threadIdx.x >> LOG;
  int n = blockIdx.x*(256>>LOG) + slot;
  int o = offs[n] & (N_EDGES-1);
  int cnt = min(deg[n], 8192);
  float acc = ldv(Xs, (n<<LOG)+c);            // prescaled self term
  int e = 0;
  for (; e+8 <= cnt; e += 8){
    int s0 = adj[o+e+0] & (N_NODES-1);
    int s1 = adj[o+e+1] & (N_NODES-1);
    int s2 = adj[o+e+2] & (N_NODES-1);
    int s3 = adj[o+e+3] & (N_NODES-1);
    int s4 = adj[o+e+4] & (N_NODES-1);
    int s5 = adj[o+e+5] & (N_NODES-1);
    int s6 = adj[o+e+6] & (N_NODES-1);
    int s7 = adj[o+e+7] & (N_NODES-1);
    float x0 = ldv(Xs, (s0<<LOG)+c);
    float x1 = ldv(Xs, (s1<<LOG)+c);
    float x2 = ldv(Xs, (s2<<LOG)+c);
    float x3 = ldv(Xs, (s3<<LOG)+c);
    float x4 = ldv(Xs, (s4<<LOG)+c);
    float x5 = ldv(Xs, (s5<<LOG)+c);
    float x6 = ldv(Xs, (s6<<LOG)+c);
    float x7 = ldv(Xs, (s7<<LOG)+c);
    acc += ((x0+x1)+(x2+x3)) + ((x4+x5)+(x6+x7));
  }
  if (e + 4 <= cnt){
    int s0 = adj[o+e+0] & (N_NODES-1);
    int s1 = adj[o+e+1] & (N_NODES-1);
    int s2 = adj[o+e+2] & (N_NODES-1);
    int s3 = adj[o+e+3] & (N_NODES-1);
    float x0 = ldv(Xs, (s0<<LOG)+c);
    float x1 = ldv(Xs, (s1<<LOG)+c);
    float x2 = ldv(Xs, (s2<<LOG)+c);
    float x3 = ldv(Xs, (s3<<LOG)+c);
    acc += (x0+x1)+(x2+x3);
    e += 4;
  }
  for (; e<cnt; e++){
    int s = adj[o+e] & (N_NODES-1);
    acc += ldv(Xs, (s<<LOG)+c);
  }
  stv(out, (n<<LOG)+c, dinv[n]*acc);
}

// ---- combine GCN weight with temporal-conv weight; write bf16 TRANSPOSED  ----
// Wtb[co][k*Kin + j] = bf16( sum_c gW[j,c] * tw[co,c,k] )  -> [64][3*Kin] dense
// braw[k*64 + co]    = sum_c gb[c] * tw[co,c,k]
template<int Kin>
__global__ __launch_bounds__(64) void k_wcomb(const void* __restrict__ gW, const void* __restrict__ gb,
                                              const void* __restrict__ tw, const int* __restrict__ flag,
                                              u16* __restrict__ Wtb, float* __restrict__ braw){
  int isbf = *flag;
  int r = blockIdx.x;
  int co = threadIdx.x;
  if (r < 3*Kin){
    int k = r / Kin, j = r % Kin;
    float acc = 0.f;
    for (int c=0; c<64; c++)
      acc += ldmix(gW, j*64+c, isbf) * ldmix(tw, co*192 + c*3 + k, isbf);
    Wtb[co*(3*Kin) + r] = f2u(acc);
  } else {
    int k = r - 3*Kin;
    float acc = 0.f;
    for (int c=0; c<64; c++)
      acc += ldmix(gb, c, isbf) * ldmix(tw, co*192 + c*3 + k, isbf);
    braw[k*64 + co] = acc;
  }
}

// ---- fused linear+temporal-conv via bf16 MFMA ----
// block = (b,v): out tile 128t x 64co, K = 3*Kin.  256 thr = 4 waves; wave w: t in [32w,32w+32).
// A im2col in LDS bf16 [130][Kin+8]; W in LDS bf16 [64][K+8] (co-major = B^T layout).
template<int Kin, typename T>
__global__ __launch_bounds__(256) void k_tconv3(const T* __restrict__ A, const u16* __restrict__ Wtb,
                                                const float* __restrict__ braw, const void* __restrict__ tb,
                                                const int* __restrict__ flag, T* __restrict__ out){
  constexpr int K  = 3*Kin;
  constexpr int SA = Kin + 8;          // u16 stride, 16B-aligned rows
  constexpr int SW = K + 8;
  constexpr int JH = Kin/2;            // dwords per At row (payload)
  constexpr int JL = (Kin==64) ? 5 : 4;
  __shared__ alignas(16) u16 At[130*SA];
  __shared__ alignas(16) u16 Wl[64*SW];
  __shared__ float ball[64], bs0[64], bs2[64];

  int isbf = *flag;
  int bid = blockIdx.x;
  int b = bid>>3, v = bid&7;
  const int tid = threadIdx.x;

  if (tid < 64){
    float b0=braw[tid], b1=braw[64+tid], b2=braw[128+tid];
    ball[tid] = ldmix(tb, tid, isbf) + b0 + b1 + b2;
    bs0[tid] = b0; bs2[tid] = b2;
  }
  // stage weights (already bf16, dense [64][K]) -> LDS padded rows
  {
    const uint32_t* Wg = (const uint32_t*)Wtb;
    uint32_t* Wd = (uint32_t*)Wl;
    for (int u=tid; u<64*(K/2); u+=256){
      int co = u/(K/2), jd = u - co*(K/2);
      Wd[co*(SW/2) + jd] = Wg[u];
    }
  }
  // stage A rows t'=t+1 in [0,130), zero-padded boundaries, fp32 -> packed bf16
  {
    uint32_t* Ad = (uint32_t*)At;
    for (int u=tid; u<130*JH; u+=256){
      int t1 = u >> JL, jd = u & (JH-1);
      int t = t1 - 1;
      uint32_t pack = 0;
      if (t >= 0 && t < 128){
        int idx = (((b*128+t)*8+v))*Kin + (jd<<1);
        float x0 = ldv(A, idx), x1 = ldv(A, idx+1);
        pack = (uint32_t)f2u(x0) | ((uint32_t)f2u(x1) << 16);
      }
      Ad[t1*(SA/2) + jd] = pack;
    }
  }
  __syncthreads();

  int wv_ = tid >> 6, lane = tid & 63;
  int q = lane >> 4, l16 = lane & 15;
  int tb0 = wv_ * 32;

  f32x4 acc[2][4];
  #pragma unroll
  for (int mt=0; mt<2; mt++)
    #pragma unroll
    for (int nt=0; nt<4; nt++)
      acc[mt][nt] = (f32x4){0.f,0.f,0.f,0.f};

  #pragma unroll
  for (int s=0; s<K/32; s++){
    int kk = (32*s)/Kin;
    int j0 = 32*s - kk*Kin;
    int col = j0 + q*8;
    bf16x8 afr[2], bfr[4];
    #pragma unroll
    for (int mt=0; mt<2; mt++){
      int row = tb0 + mt*16 + l16 + kk;
      afr[mt] = *(const bf16x8*)&At[row*SA + col];
    }
    #pragma unroll
    for (int nt=0; nt<4; nt++){
      int co = nt*16 + l16;
      bfr[nt] = *(const bf16x8*)&Wl[co*SW + 32*s + q*8];
    }
    #pragma unroll
    for (int mt=0; mt<2; mt++)
      #pragma unroll
      for (int nt=0; nt<4; nt++)
        acc[mt][nt] = __builtin_amdgcn_mfma_f32_16x16x32_bf16(afr[mt], bfr[nt], acc[mt][nt], 0, 0, 0);
  }

  // epilogue: D[m][n] -> lane holds col n=l16, rows m=q*4+r
  #pragma unroll
  for (int mt=0; mt<2; mt++){
    #pragma unroll
    for (int r=0; r<4; r++){
      int t = tb0 + mt*16 + q*4 + r;
      int base = (((b*128+t)*8+v)) << 6;
      #pragma unroll
      for (int nt=0; nt<4; nt++){
        int co = nt*16 + l16;
        float val = acc[mt][nt][r] + ball[co];
        if (t == 0)   val -= bs0[co];
        if (t == 127) val -= bs2[co];
        stv(out, base + co, val);
      }
    }
  }
}

// ---- BN stats: per-channel sum / sumsq (float4) ----
template<typename T>
__global__ __launch_bounds__(256) void k_stats(const T* __restrict__ X, float* __restrict__ stats){
  int cq = (threadIdx.x & 15) << 2;   // co-quad
  int g  = threadIdx.x >> 4;          // 16 row-groups
  float4 s  = make_float4(0.f,0.f,0.f,0.f);
  float4 s2 = make_float4(0.f,0.f,0.f,0.f);
  for (int row = blockIdx.x*16 + g; row < N_NODES; row += gridDim.x*16){
    float4 v = ld4(X, (row<<6) + cq);
    s.x += v.x; s.y += v.y; s.z += v.z; s.w += v.w;
    s2.x += v.x*v.x; s2.y += v.y*v.y; s2.z += v.z*v.z; s2.w += v.w*v.w;
  }
  __shared__ float sh[16][64], sh2[16][64];
  *(float4*)&sh[g][cq]  = s;
  *(float4*)&sh2[g][cq] = s2;
  __syncthreads();
  if (threadIdx.x < 64){
    int co = threadIdx.x;
    float a = 0.f, a2 = 0.f;
    #pragma unroll
    for (int gg=0; gg<16; gg++){ a += sh[gg][co]; a2 += sh2[gg][co]; }
    atomicAdd(&stats[co], a);
    atomicAdd(&stats[64+co], a2);
  }
}

// ---- BN-apply + ReLU + 1x1 conv + tanh (+ optional dinv-prescale) + scrambled view write ----
template<typename T>
__global__ __launch_bounds__(256) void k_bnfuse(const T* __restrict__ X, const float* __restrict__ stats,
                                                const void* __restrict__ gam, const void* __restrict__ bet,
                                                const void* __restrict__ ow, const void* __restrict__ ob,
                                                const int* __restrict__ flag, const float* __restrict__ presc,
                                                T* __restrict__ out){
  __shared__ float y_s[64*68];     // stride 68: 16B-aligned float4 per ci-quad
  __shared__ float ow_s[64*64];    // [co][ci]
  __shared__ float kk[64], bsh[64];
  int isbf = *flag;
  int bid = blockIdx.x;
  int b = bid>>4, rem = bid&15, v = rem>>1, thi = rem&1;
  int t0 = thi<<6;
  const float invM = 1.0f/131072.0f;
  if (threadIdx.x < 64){
    int ci = threadIdx.x;
    float mu = stats[ci]*invM;
    float var = stats[64+ci]*invM - mu*mu;
    float rs = rsqrtf(fmaxf(var, 0.f) + 1e-5f);
    float kv = rs*ldmix(gam, ci, isbf);
    kk[ci] = kv;
    bsh[ci] = ldmix(bet, ci, isbf) - mu*kv;
  }
  for (int u=threadIdx.x; u<1024; u+=256){
    int r = u>>4, cq = (u&15)<<2;
    *(float4*)&ow_s[(r<<6)+cq] = ld4mix(ow, (r<<6)+cq, isbf);
  }
  __syncthreads();
  for (int u=threadIdx.x; u<1024; u+=256){
    int tl = u>>4, cq = (u&15)<<2;
    int t = t0 + tl;
    float4 val = ld4(X, (((b*128+t)*8+v)<<6) + cq);
    float4 kq = *(const float4*)&kk[cq];
    float4 bq = *(const float4*)&bsh[cq];
    val.x = fmaxf(val.x*kq.x + bq.x, 0.f);
    val.y = fmaxf(val.y*kq.y + bq.y, 0.f);
    val.z = fmaxf(val.z*kq.z + bq.z, 0.f);
    val.w = fmaxf(val.w*kq.w + bq.w, 0.f);
    *(float4*)&y_s[tl*68 + cq] = val;
  }
  __syncthreads();
  int l = threadIdx.x & 63, wg = threadIdx.x >> 6;
  float acc[16];
  #pragma unroll
  for (int c8=0; c8<16; c8++) acc[c8] = ldmix(ob, wg*16 + c8, isbf);
  for (int ci=0; ci<64; ci+=4){
    float4 y4 = *(const float4*)&y_s[l*68 + ci];
    #pragma unroll
    for (int c8=0; c8<16; c8++){
      float4 w4 = *(const float4*)&ow_s[((wg*16+c8)<<6) + ci];
      acc[c8] += y4.x*w4.x + y4.y*w4.y + y4.z*w4.z + y4.w*w4.w;
    }
  }
  #pragma unroll
  for (int c8=0; c8<16; c8++){
    int co = wg*16 + c8;
    float z = tanhf(acc[c8]);
    int r = (b<<10) + (co<<4) + (v<<1) + thi;
    if (presc) z *= presc[r];     // lane-uniform broadcast
    stv(out, (r<<6) + l, z);
  }
}

// ---- final: out[b,v] = mean_{t,f}( x3 @ reg_w + reg_b ) ----
template<typename T>
__global__ __launch_bounds__(256) void k_final(const T* __restrict__ X, const void* __restrict__ rw,
                                               const void* __restrict__ rb, const int* __restrict__ flag,
                                               void* __restrict__ out){
  __shared__ float rw_s[64];
  __shared__ float rbs_s;
  __shared__ float wred[4];
  int isbf = *flag;
  int bid = blockIdx.x;
  int b = bid>>3, v = bid&7;
  if (threadIdx.x < 64){
    float s = 0.f;
    #pragma unroll
    for (int f=0; f<8; f++) s += ldmix(rw, threadIdx.x*8 + f, isbf);
    rw_s[threadIdx.x] = s;
  }
  if (threadIdx.x == 0){
    float s = 0.f;
    for (int f=0; f<8; f++) s += ldmix(rb, f, isbf);
    rbs_s = s;
  }
  __syncthreads();
  float acc = 0.f;
  for (int i=threadIdx.x; i<128*64; i+=256){
    int t = i>>6, j = i&63;
    acc += ldv(X, (((b*128+t)*8+v)<<6) + j) * rw_s[j];
  }
  for (int off=32; off; off>>=1) acc += __shfl_down(acc, off);
  if ((threadIdx.x & 63) == 0) wred[threadIdx.x>>6] = acc;
  __syncthreads();
  if (threadIdx.x == 0){
    float r = wred[0]+wred[1]+wred[2]+wred[3];
    float val = r*(1.0f/1024.0f) + rbs_s*0.125f;
    if (isbf) ((u16*)out)[bid] = f2u(val);
    else      ((float*)out)[bid] = val;
  }
}

// ---------------- host pipeline ----------------
template<typename T>
static void run_pipe(void* const* d_in, void* out, char* p, hipStream_t stream){
  auto alloc = [&](size_t bytes){ void* r = (void*)p; p += (bytes + 255) & ~(size_t)255; return r; };
  T*     A    = (T*)    alloc(sizeof(T)*(size_t)N_NODES*64);
  T*     B    = (T*)    alloc(sizeof(T)*(size_t)N_NODES*64);
  int*   deg  = (int*)  alloc(sizeof(int)*N_NODES);
  float* dinv = (float*)alloc(sizeof(float)*N_NODES);
  int*   offs = (int*)  alloc(sizeof(int)*N_NODES);
  int*   cur  = (int*)  alloc(sizeof(int)*N_NODES);
  int*   adj  = (int*)  alloc(sizeof(int)*N_EDGES);
  int*   bsum = (int*)  alloc(sizeof(int)*512);
  float* stats= (float*)alloc(sizeof(float)*128);
  int*   flag = (int*)  alloc(sizeof(int)*64);
  u16*   Wtb  = (u16*)  alloc(sizeof(u16)*192*64);
  float* braw = (float*)alloc(sizeof(float)*192);

  const void* x   = d_in[0];
  const int* edge = (const int*)d_in[1];
  const void* g1w = d_in[2];  const void* g1b = d_in[3];
  const void* t1w = d_in[4];  const void* t1b = d_in[5];
  const void* bn1g= d_in[6];  const void* bn1b= d_in[7];
  const void* o1w = d_in[8];  const void* o1b = d_in[9];
  const void* g2w = d_in[10]; const void* g2b = d_in[11];
  const void* t2w = d_in[12]; const void* t2b = d_in[13];
  const void* bn2g= d_in[14]; const void* bn2b= d_in[15];
  const void* o2w = d_in[16]; const void* o2b = d_in[17];
  const void* rw  = d_in[18]; const void* rb  = d_in[19];
  const int* src = edge;
  const int* dst = edge + N_EDGES;

  k_detect<<<1, 64, 0, stream>>>((const uint32_t*)x, flag);

  // graph prep
  hipMemsetAsync(deg, 0, sizeof(int)*N_NODES, stream);
  k_count<<<N_EDGES/256, 256, 0, stream>>>(dst, deg);
  k_dinv <<<N_NODES/256, 256, 0, stream>>>(deg, dinv);
  k_scan1<<<512, 256, 0, stream>>>(deg, offs, bsum);
  k_scan2<<<1, 512, 0, stream>>>(bsum);
  k_scan3<<<512, 256, 0, stream>>>(offs, bsum);
  hipMemsetAsync(cur, 0, sizeof(int)*N_NODES, stream);
  k_fill <<<N_EDGES/256, 256, 0, stream>>>(src, dst, offs, cur, adj);

  // ---- layer 1 ----
  k_prescale<T>  <<<N_NODES*32/256, 256, 0, stream>>>(x, flag, dinv, B);   // B = dinv*x  [N,32]
  k_aggp<32,T>   <<<N_NODES/8, 256, 0, stream>>>(B, adj, offs, deg, dinv, A);
  k_wcomb<32>    <<<3*32+3, 64, 0, stream>>>(g1w, g1b, t1w, flag, Wtb, braw);
  k_tconv3<32,T> <<<1024, 256, 0, stream>>>(A, Wtb, braw, t1b, flag, B);
  hipMemsetAsync(stats, 0, sizeof(float)*128, stream);
  k_stats<T>     <<<512, 256, 0, stream>>>(B, stats);
  k_bnfuse<T>    <<<2048, 256, 0, stream>>>(B, stats, bn1g, bn1b, o1w, o1b, flag, dinv, A);  // A prescaled

  // ---- layer 2 ----
  k_aggp<64,T>   <<<N_NODES/4, 256, 0, stream>>>(A, adj, offs, deg, dinv, B);
  k_wcomb<64>    <<<3*64+3, 64, 0, stream>>>(g2w, g2b, t2w, flag, Wtb, braw);
  k_tconv3<64,T> <<<1024, 256, 0, stream>>>(B, Wtb, braw, t2b, flag, A);
  hipMemsetAsync(stats, 0, sizeof(float)*128, stream);
  k_stats<T>     <<<512, 256, 0, stream>>>(A, stats);
  k_bnfuse<T>    <<<2048, 256, 0, stream>>>(A, stats, bn2g, bn2b, o2w, o2b, flag, (const float*)nullptr, B);

  // ---- regression + mean ----
  k_final<T><<<1024, 256, 0, stream>>>(B, rw, rb, flag, out);
}

extern "C" void kernel_launch(void* const* d_in, const int* in_sizes, int n_in,
                              void* d_out, int out_size, void* d_ws, size_t ws_size,
                              hipStream_t stream){
  (void)in_sizes; (void)n_in; (void)out_size;
  const size_t csr_bytes = 4*sizeof(int)*(size_t)N_NODES + sizeof(int)*(size_t)N_EDGES + 131072;
  const size_t need_f32  = 2*sizeof(float)*(size_t)N_NODES*64 + csr_bytes;   // ~73.5 MB
  if (ws_size >= need_f32)
    run_pipe<float>(d_in, d_out, (char*)d_ws, stream);
  else
    run_pipe<u16>(d_in, d_out, (char*)d_ws, stream);
}